// Round 2
// baseline (1511.234 us; speedup 1.0000x reference)
//
#include <hip/hip_runtime.h>
#include <hip/hip_bf16.h>
#include <math.h>

#define DEVINL __device__ __forceinline__

typedef __attribute__((ext_vector_type(4))) float  f32x4;
typedef __attribute__((ext_vector_type(8))) __bf16 bf16x8;
typedef __attribute__((ext_vector_type(8))) unsigned short ushort8;

DEVINL float b2f(unsigned short u) {
    union { unsigned int i; float f; } v; v.i = ((unsigned int)u) << 16; return v.f;
}
DEVINL unsigned short f2b(float f) {
    union { float f; unsigned int i; } v; v.f = f;
    unsigned int u = v.i;
    unsigned int r = (u + 0x7fffu + ((u >> 16) & 1u)) >> 16;
    return (unsigned short)r;
}
DEVINL float gelu_exact(float x) {
    return 0.5f * x * (1.0f + erff(x * 0.70710678118654752440f));
}

// ---------------------------------------------------------------------------
// conv1 (Cin=8 -> 256, k=3, pad=1) + ReLU, output bf16
__global__ __launch_bounds__(256) void conv1_kernel(
    const float* __restrict__ x, const float* __restrict__ w,
    const float* __restrict__ bias, unsigned short* __restrict__ h1)
{
    __shared__ float xs[24];
    int bl = blockIdx.x; int b = bl / 400, l = bl % 400;
    int t = threadIdx.x;
    if (t < 24) {
        int dt = t / 8, c = t % 8;
        int lp = l + dt - 1;
        xs[t] = (lp >= 0 && lp < 400) ? x[((size_t)b * 400 + lp) * 8 + c] : 0.0f;
    }
    __syncthreads();
    float acc = bias[t];
#pragma unroll
    for (int dt = 0; dt < 3; ++dt)
#pragma unroll
        for (int c = 0; c < 8; ++c)
            acc += xs[dt * 8 + c] * w[t * 24 + c * 3 + dt];
    h1[(size_t)bl * 256 + t] = f2b(fmaxf(acc, 0.0f));
}

// conv2 weight reorder (o, ci, t) -> w2r[o, t*256+ci] bf16
__global__ void reorder_w2_kernel(const float* __restrict__ w, unsigned short* __restrict__ out)
{
    int idx = blockIdx.x * 256 + threadIdx.x;
    if (idx >= 256 * 768) return;
    int o = idx / 768, r = idx % 768;
    int tpos = r / 256, ci = r % 256;
    out[idx] = f2b(w[o * 768 + ci * 3 + tpos]);
}

__global__ void castw_kernel(const float* __restrict__ in, unsigned short* __restrict__ out, int n)
{
    int i = blockIdx.x * 256 + threadIdx.x;
    if (i < n) out[i] = f2b(in[i]);
}

// ---------------------------------------------------------------------------
// LayerNorm over dm=256 per row, fp32 in -> bf16 out. 4 rows/block (1/wave).
__global__ __launch_bounds__(256) void ln_kernel(
    const float* __restrict__ h, const float* __restrict__ g,
    const float* __restrict__ bta, unsigned short* __restrict__ out)
{
    int w = threadIdx.x >> 6, l = threadIdx.x & 63;
    int row = blockIdx.x * 4 + w;
    const float* p = h + (size_t)row * 256 + l * 4;
    float4 v = *(const float4*)p;
    float s  = v.x + v.y + v.z + v.w;
    float s2 = v.x * v.x + v.y * v.y + v.z * v.z + v.w * v.w;
#pragma unroll
    for (int m = 1; m < 64; m <<= 1) { s += __shfl_xor(s, m); s2 += __shfl_xor(s2, m); }
    float mu = s * (1.0f / 256.0f);
    float var = s2 * (1.0f / 256.0f) - mu * mu;
    float rs = rsqrtf(var + 1e-5f);
    float4 gg = *(const float4*)(g + l * 4);
    float4 bb = *(const float4*)(bta + l * 4);
    ushort4 o;
    o.x = f2b((v.x - mu) * rs * gg.x + bb.x);
    o.y = f2b((v.y - mu) * rs * gg.y + bb.y);
    o.z = f2b((v.z - mu) * rs * gg.z + bb.z);
    o.w = f2b((v.w - mu) * rs * gg.w + bb.w);
    *(ushort4*)(out + (size_t)row * 256 + l * 4) = o;
}

// ---------------------------------------------------------------------------
// bf16 GEMM: C(MxN) = A(MxK, lda) * Bt(NxK)^T, epilogue variants.
// EPI 0: +bias, store bf16.  1: +bias, GELU, store bf16.  3: +bias+res, store fp32.
template <int EPI>
__global__ __launch_bounds__(256) void gemm_bt(
    const unsigned short* __restrict__ A, const unsigned short* __restrict__ Bt,
    const float* __restrict__ bias, const float* __restrict__ res,
    void* __restrict__ Cout, int N, int K, int lda, int ldc)
{
    __shared__ unsigned short As[128 * 64];
    __shared__ unsigned short Bs[128 * 64];
    const int nbn = N >> 7;
    int bm = blockIdx.x / nbn, bn = blockIdx.x % nbn;
    int t = threadIdx.x, l = t & 63, w = t >> 6;
    int wm = w & 1, wn = w >> 1;
    f32x4 acc[4][4] = {};
    const int ktn = K >> 6;
    for (int kt = 0; kt < ktn; ++kt) {
#pragma unroll
        for (int i = 0; i < 4; ++i) {
            int off = (i * 256 + t) * 8;
            int row = off >> 6, col = off & 63;
            ushort8 va = *(const ushort8*)(A + (size_t)(bm * 128 + row) * lda + kt * 64 + col);
            *(ushort8*)(As + off) = va;
            ushort8 vb = *(const ushort8*)(Bt + (size_t)(bn * 128 + row) * K + kt * 64 + col);
            *(ushort8*)(Bs + off) = vb;
        }
        __syncthreads();
#pragma unroll
        for (int kk = 0; kk < 2; ++kk) {
            bf16x8 af[4], bfr[4];
#pragma unroll
            for (int i = 0; i < 4; ++i) {
                af[i]  = *(const bf16x8*)(As + (wm * 64 + i * 16 + (l & 15)) * 64 + kk * 32 + (l >> 4) * 8);
                bfr[i] = *(const bf16x8*)(Bs + (wn * 64 + i * 16 + (l & 15)) * 64 + kk * 32 + (l >> 4) * 8);
            }
#pragma unroll
            for (int i = 0; i < 4; ++i)
#pragma unroll
                for (int j = 0; j < 4; ++j)
                    acc[i][j] = __builtin_amdgcn_mfma_f32_16x16x32_bf16(af[i], bfr[j], acc[i][j], 0, 0, 0);
        }
        __syncthreads();
    }
    int r0 = bm * 128 + wm * 64 + (l >> 4) * 4;
    int c0 = bn * 128 + wn * 64 + (l & 15);
#pragma unroll
    for (int i = 0; i < 4; ++i) {
#pragma unroll
        for (int j = 0; j < 4; ++j) {
            int col = c0 + j * 16;
            float bb = bias[col];
#pragma unroll
            for (int q = 0; q < 4; ++q) {
                int row = r0 + i * 16 + q;
                size_t idx = (size_t)row * ldc + col;
                float v = acc[i][j][q] + bb;
                if (EPI == 0)       ((unsigned short*)Cout)[idx] = f2b(v);
                else if (EPI == 1)  ((unsigned short*)Cout)[idx] = f2b(gelu_exact(v));
                else                ((float*)Cout)[idx] = v + res[idx];
            }
        }
    }
}

// ---------------------------------------------------------------------------
// conv2 as GEMM with FUSED im2col staging: C(M x 256) = im2col(h1)(M x 768) @ W2r^T.
// Each 64-wide K-slice has constant tap tpos = kt>>2; A-tile load is a shifted
// row of h1 with zero boundary masking. ReLU epilogue, fp32 out.
__global__ __launch_bounds__(256) void gemm_conv2(
    const unsigned short* __restrict__ h1, const unsigned short* __restrict__ Bt,
    const float* __restrict__ bias, float* __restrict__ Cout)
{
    __shared__ unsigned short As[128 * 64];
    __shared__ unsigned short Bs[128 * 64];
    int bm = blockIdx.x >> 1, bn = blockIdx.x & 1;
    int t = threadIdx.x, l = t & 63, w = t >> 6;
    int wm = w & 1, wn = w >> 1;
    f32x4 acc[4][4] = {};
    for (int kt = 0; kt < 12; ++kt) {
        int tpos = kt >> 2;          // tap 0..2
        int cbase = (kt & 3) * 64;   // channel base 0..192
#pragma unroll
        for (int i = 0; i < 4; ++i) {
            int off = (i * 256 + t) * 8;
            int row = off >> 6, col = off & 63;
            int m = bm * 128 + row;
            int b = m / 400, ll = m % 400;
            int lp = ll + tpos - 1;
            ushort8 va = (ushort8)0;
            if (lp >= 0 && lp < 400)
                va = *(const ushort8*)(h1 + ((size_t)(b * 400 + lp) * 256 + cbase + col));
            *(ushort8*)(As + off) = va;
            ushort8 vb = *(const ushort8*)(Bt + (size_t)(bn * 128 + row) * 768 + kt * 64 + col);
            *(ushort8*)(Bs + off) = vb;
        }
        __syncthreads();
#pragma unroll
        for (int kk = 0; kk < 2; ++kk) {
            bf16x8 af[4], bfr[4];
#pragma unroll
            for (int i = 0; i < 4; ++i) {
                af[i]  = *(const bf16x8*)(As + (wm * 64 + i * 16 + (l & 15)) * 64 + kk * 32 + (l >> 4) * 8);
                bfr[i] = *(const bf16x8*)(Bs + (wn * 64 + i * 16 + (l & 15)) * 64 + kk * 32 + (l >> 4) * 8);
            }
#pragma unroll
            for (int i = 0; i < 4; ++i)
#pragma unroll
                for (int j = 0; j < 4; ++j)
                    acc[i][j] = __builtin_amdgcn_mfma_f32_16x16x32_bf16(af[i], bfr[j], acc[i][j], 0, 0, 0);
        }
        __syncthreads();
    }
    int r0 = bm * 128 + wm * 64 + (l >> 4) * 4;
    int c0 = bn * 128 + wn * 64 + (l & 15);
#pragma unroll
    for (int i = 0; i < 4; ++i)
#pragma unroll
        for (int j = 0; j < 4; ++j) {
            int col = c0 + j * 16;
            float bb = bias[col];
#pragma unroll
            for (int q = 0; q < 4; ++q) {
                int row = r0 + i * 16 + q;
                Cout[(size_t)row * 256 + col] = fmaxf(acc[i][j][q] + bb, 0.0f);
            }
        }
}

// ---------------------------------------------------------------------------
// depthwise conv (k=3, pad=1, per-channel over L) + GELU; bf16 in/out, 2 ch/thread
__global__ __launch_bounds__(256) void dwconv_kernel(
    const unsigned short* __restrict__ xp, const float* __restrict__ w,
    const float* __restrict__ bias, unsigned short* __restrict__ out)
{
    int bl = blockIdx.x; int b = bl / 400, l = bl % 400;
    int t = threadIdx.x;
    int c = t * 2;
    float acc0 = bias[c], acc1 = bias[c + 1];
#pragma unroll
    for (int dt = 0; dt < 3; ++dt) {
        int lp = l + dt - 1;
        if (lp < 0 || lp >= 400) continue;
        unsigned int v = *(const unsigned int*)(xp + ((size_t)(b * 400 + lp) * 512 + c));
        acc0 += b2f((unsigned short)(v & 0xffff)) * w[c * 3 + dt];
        acc1 += b2f((unsigned short)(v >> 16)) * w[(c + 1) * 3 + dt];
    }
    unsigned int o = (unsigned int)f2b(gelu_exact(acc0)) | ((unsigned int)f2b(gelu_exact(acc1)) << 16);
    *(unsigned int*)(out + (size_t)bl * 512 + c) = o;
}

// ---------------------------------------------------------------------------
// xproj: BC(m,32) = tanh(x_conv(m,512) @ W^T(32x512) + b). 8 rows/block.
__global__ __launch_bounds__(256) void xproj_kernel(
    const unsigned short* __restrict__ xc, const unsigned short* __restrict__ w,
    const float* __restrict__ bias, float* __restrict__ BC)
{
    __shared__ unsigned short wsh[32 * 516];
    __shared__ unsigned short xs[8 * 512];
    int t = threadIdx.x;
    int m = blockIdx.x * 8;
    for (int i = t; i < 4096; i += 256) {   // 32*512/4 pieces of 4
        int e = i * 4; int j = e / 512, k = e % 512;
        *(ushort4*)(wsh + j * 516 + k) = *(const ushort4*)(w + j * 512 + k);
    }
    for (int i = t; i < 1024; i += 256) {   // 8*512/4
        int e = i * 4;
        *(ushort4*)(xs + e) = *(const ushort4*)(xc + (size_t)m * 512 + e);
    }
    __syncthreads();
    int r = t >> 5, j = t & 31;
    const unsigned short* wr = wsh + j * 516;
    const unsigned short* xr = xs + r * 512;
    float acc = 0.0f;
#pragma unroll 8
    for (int k = 0; k < 512; k += 4) {
        ushort4 w4 = *(const ushort4*)(wr + k);
        ushort4 x4 = *(const ushort4*)(xr + k);
        acc += b2f(w4.x) * b2f(x4.x) + b2f(w4.y) * b2f(x4.y) +
               b2f(w4.z) * b2f(x4.z) + b2f(w4.w) * b2f(x4.w);
    }
    BC[(size_t)(m + r) * 32 + j] = tanhf(acc + bias[j]);
}

// ---------------------------------------------------------------------------
// Sequential SSM scan. 1 block per batch, 512 threads (thread t = channel d).
__global__ __launch_bounds__(512) void scan_kernel(
    const float* __restrict__ BC, const unsigned short* __restrict__ xconv,
    const unsigned short* __restrict__ gres, const float* __restrict__ Aw,
    const float* __restrict__ Dw, const float* __restrict__ sng,
    const float* __restrict__ snb, unsigned short* __restrict__ yg)
{
    __shared__ float lds_bc[32];
    __shared__ float lds_red[16];
    int b = blockIdx.x, t = threadIdx.x;
    float st[16], tA[16], g[16], bb[16];
#pragma unroll
    for (int j = 0; j < 16; ++j) {
        st[j] = 0.0f;
        tA[j] = tanhf(Aw[t * 16 + j]);
        g[j]  = sng[t * 16 + j];
        bb[j] = snb[t * 16 + j];
    }
    float Dd = Dw[t];
    const size_t base = (size_t)b * 400;
    float bc_reg = (t < 32) ? BC[base * 32 + t] : 0.0f;
    float xt_f = b2f(xconv[base * 512 + t]);
    float gr_f = b2f(gres[base * 512 + t]);
    for (int l = 0; l < 400; ++l) {
        if (t < 32) lds_bc[t] = bc_reg;
        __syncthreads();
        float Btv[16], Ctv[16];
#pragma unroll
        for (int j = 0; j < 16; ++j) { Btv[j] = lds_bc[j]; Ctv[j] = lds_bc[16 + j]; }
        int ln = (l + 1 < 400) ? l + 1 : 399;
        if (t < 32) bc_reg = BC[(base + ln) * 32 + t];
        float xt = xt_f, gr = gr_f;
        xt_f = b2f(xconv[(base + ln) * 512 + t]);
        gr_f = b2f(gres[(base + ln) * 512 + t]);
        float out = xt * Dd;
#pragma unroll
        for (int j = 0; j < 16; ++j) { st[j] += Btv[j]; out += st[j] * Ctv[j]; }
        yg[(base + l) * 512 + t] = f2b(out * gr);
        float s1 = 0.0f, s2 = 0.0f;
#pragma unroll
        for (int j = 0; j < 16; ++j) { st[j] *= tA[j]; s1 += st[j]; s2 += st[j] * st[j]; }
#pragma unroll
        for (int m = 1; m < 64; m <<= 1) { s1 += __shfl_xor(s1, m); s2 += __shfl_xor(s2, m); }
        if ((t & 63) == 0) { lds_red[(t >> 6) * 2] = s1; lds_red[(t >> 6) * 2 + 1] = s2; }
        __syncthreads();
        float S1 = 0.0f, S2 = 0.0f;
#pragma unroll
        for (int wv = 0; wv < 8; ++wv) { S1 += lds_red[wv * 2]; S2 += lds_red[wv * 2 + 1]; }
        float mu = S1 * (1.0f / 8192.0f);
        float var = S2 * (1.0f / 8192.0f) - mu * mu;
        float rs = rsqrtf(var + 1e-5f);
#pragma unroll
        for (int j = 0; j < 16; ++j) st[j] = (st[j] - mu) * rs * g[j] + bb[j];
    }
}

// ---------------------------------------------------------------------------
// mean over L then FC (37 classes). 1 block per batch.
__global__ __launch_bounds__(256) void poolfc_kernel(
    const float* __restrict__ h, const float* __restrict__ fcw,
    const float* __restrict__ fcb, float* __restrict__ out)
{
    __shared__ float ps[256];
    int b = blockIdx.x, t = threadIdx.x;
    float s = 0.0f;
    for (int l = 0; l < 400; ++l) s += h[((size_t)b * 400 + l) * 256 + t];
    ps[t] = s * (1.0f / 400.0f);
    __syncthreads();
    if (t < 37) {
        float acc = fcb[t];
        for (int o = 0; o < 256; ++o) acc += ps[o] * fcw[t * 256 + o];
        out[b * 37 + t] = acc;
    }
}

// ---------------------------------------------------------------------------
extern "C" void kernel_launch(void* const* d_in, const int* in_sizes, int n_in,
                              void* d_out, int out_size, void* d_ws, size_t ws_size,
                              hipStream_t stream)
{
    const float* x         = (const float*)d_in[0];
    const float* conv1_w   = (const float*)d_in[1];
    const float* conv1_b   = (const float*)d_in[2];
    const float* conv2_w   = (const float*)d_in[3];
    const float* conv2_b   = (const float*)d_in[4];
    const float* ln_g      = (const float*)d_in[5];
    const float* ln_b      = (const float*)d_in[6];
    const float* inproj_w  = (const float*)d_in[7];
    const float* inproj_b  = (const float*)d_in[8];
    const float* dw_w      = (const float*)d_in[9];
    const float* dw_b      = (const float*)d_in[10];
    const float* xproj_w   = (const float*)d_in[11];
    const float* xproj_b   = (const float*)d_in[12];
    const float* A         = (const float*)d_in[13];
    const float* D         = (const float*)d_in[14];
    const float* sn_g      = (const float*)d_in[15];
    const float* sn_b      = (const float*)d_in[16];
    const float* outproj_w = (const float*)d_in[17];
    const float* outproj_b = (const float*)d_in[18];
    const float* fc_w      = (const float*)d_in[19];
    const float* fc_b      = (const float*)d_in[20];
    float* out = (float*)d_out;

    const int M = 51200; // B*L

    // Workspace layout — total 243,007,488 B (fits a 256 MiB scratch).
    // off 0          : h    52,428,800  fp32 M*256   (persistent residual)
    // off 52428800   : hn   26,214,400  bf16 M*256   | h1 aliases (prologue)
    // off 78643200   : xp_c 52,428,800  bf16 M*512   | yg aliases (post-dwconv)
    // off 131072000  : grs  52,428,800  bf16 M*512
    // off 183500800  : xcv  52,428,800  bf16 M*512
    // off 235929600  : BC    6,553,600  fp32 M*32
    // off 242483200  : wbuf    524,288  bf16 weights
    if (ws_size < 243007488u) return;  // diagnostic guard: clean fail, not a fault
    char* ws = (char*)d_ws;
    float*          h    = (float*)(ws);
    unsigned short* hn   = (unsigned short*)(ws + 52428800);
    unsigned short* h1   = (unsigned short*)(ws + 52428800);
    unsigned short* xp_c = (unsigned short*)(ws + 78643200);
    unsigned short* yg   = (unsigned short*)(ws + 78643200);
    unsigned short* grs  = (unsigned short*)(ws + 131072000);
    unsigned short* xcv  = (unsigned short*)(ws + 183500800);
    float*          BC   = (float*)(ws + 235929600);
    unsigned short* wbuf = (unsigned short*)(ws + 242483200);

    // conv1 + relu -> h1 (bf16)
    conv1_kernel<<<M, 256, 0, stream>>>(x, conv1_w, conv1_b, h1);
    // conv2 weights reorder -> wbuf; conv2 GEMM (fused im2col) + relu -> h (fp32)
    reorder_w2_kernel<<<768, 256, 0, stream>>>(conv2_w, wbuf);
    gemm_conv2<<<(M / 128) * 2, 256, 0, stream>>>(h1, wbuf, conv2_b, h);

    for (int i = 0; i < 2; ++i) {
        // LN -> hn (bf16)   (overwrites h1 alias — h1 is dead by now)
        ln_kernel<<<M / 4, 256, 0, stream>>>(h, ln_g + i * 256, ln_b + i * 256, hn);
        // inproj weights -> wbuf
        castw_kernel<<<1024, 256, 0, stream>>>(inproj_w + (size_t)i * 262144, wbuf, 262144);
        // inproj first half -> xp_c (bf16)
        gemm_bt<0><<<(M / 128) * 4, 256, 0, stream>>>(hn, wbuf, inproj_b + i * 1024, nullptr,
                                                      xp_c, 512, 256, 256, 512);
        // inproj second half + GELU -> grs (bf16)
        gemm_bt<1><<<(M / 128) * 4, 256, 0, stream>>>(hn, wbuf + 131072, inproj_b + i * 1024 + 512,
                                                      nullptr, grs, 512, 256, 256, 512);
        // depthwise conv + gelu -> xcv
        dwconv_kernel<<<M, 256, 0, stream>>>(xp_c, dw_w + i * 1536, dw_b + i * 512, xcv);
        // xproj -> BC (tanh applied)
        castw_kernel<<<64, 256, 0, stream>>>(xproj_w + i * 16384, wbuf, 16384);
        xproj_kernel<<<M / 8, 256, 0, stream>>>(xcv, wbuf, xproj_b + i * 32, BC);
        // sequential scan -> yg = ssm_out * gres   (yg aliases xp_c — dead now)
        scan_kernel<<<128, 512, 0, stream>>>(BC, xcv, grs, A + i * 8192, D + i * 512,
                                             sn_g + i * 8192, sn_b + i * 8192, yg);
        // outproj + residual -> h (fp32, in place)
        castw_kernel<<<512, 256, 0, stream>>>(outproj_w + (size_t)i * 131072, wbuf, 131072);
        gemm_bt<3><<<(M / 128) * 2, 256, 0, stream>>>(yg, wbuf, outproj_b + i * 256, h, h,
                                                      256, 512, 512, 256);
    }
    // pool + fc
    poolfc_kernel<<<128, 256, 0, stream>>>(h, fc_w, fc_b, out);
}

// Round 3
// 1402.334 us; speedup vs baseline: 1.0777x; 1.0777x over previous
//
#include <hip/hip_runtime.h>
#include <hip/hip_bf16.h>
#include <math.h>

#define DEVINL __device__ __forceinline__

typedef __attribute__((ext_vector_type(4))) float  f32x4;
typedef __attribute__((ext_vector_type(8))) __bf16 bf16x8;
typedef __attribute__((ext_vector_type(8))) unsigned short ushort8;

DEVINL float b2f(unsigned short u) {
    union { unsigned int i; float f; } v; v.i = ((unsigned int)u) << 16; return v.f;
}
DEVINL unsigned short f2b(float f) {
    union { float f; unsigned int i; } v; v.f = f;
    unsigned int u = v.i;
    unsigned int r = (u + 0x7fffu + ((u >> 16) & 1u)) >> 16;
    return (unsigned short)r;
}
DEVINL float gelu_exact(float x) {
    return 0.5f * x * (1.0f + erff(x * 0.70710678118654752440f));
}

// ---------------------------------------------------------------------------
// conv1 (Cin=8 -> 256, k=3, pad=1) + ReLU, output bf16.
// 1024 blocks = 128 batches x 8 tiles of 50 positions; thread = out channel.
// Weights hoisted to registers once per block; x window staged in LDS.
__global__ __launch_bounds__(256) void conv1_kernel(
    const float* __restrict__ x, const float* __restrict__ w,
    const float* __restrict__ bias, unsigned short* __restrict__ h1)
{
    __shared__ float xs[52 * 8];
    int b = blockIdx.x >> 3, tile = blockIdx.x & 7;
    int p0 = tile * 50;
    int t = threadIdx.x;
    for (int i = t; i < 416; i += 256) {
        int p = i >> 3, c = i & 7;
        int lp = p0 + p - 1;
        xs[i] = (lp >= 0 && lp < 400) ? x[((size_t)b * 400 + lp) * 8 + c] : 0.0f;
    }
    float wr[24];
    const float4* wp = (const float4*)(w + t * 24);   // 24 floats = 96B, 16B-aligned
#pragma unroll
    for (int i = 0; i < 6; ++i) {
        float4 v4 = wp[i];
        wr[i * 4] = v4.x; wr[i * 4 + 1] = v4.y; wr[i * 4 + 2] = v4.z; wr[i * 4 + 3] = v4.w;
    }
    float bs = bias[t];
    __syncthreads();
#pragma unroll 2
    for (int p = 0; p < 50; ++p) {
        float acc = bs;
#pragma unroll
        for (int dt = 0; dt < 3; ++dt)
#pragma unroll
            for (int c = 0; c < 8; ++c)
                acc += xs[(p + dt) * 8 + c] * wr[c * 3 + dt];
        h1[((size_t)b * 400 + p0 + p) * 256 + t] = f2b(fmaxf(acc, 0.0f));
    }
}

// conv2 weight reorder (o, ci, t) -> w2r[o, t*256+ci] bf16
__global__ void reorder_w2_kernel(const float* __restrict__ w, unsigned short* __restrict__ out)
{
    int idx = blockIdx.x * 256 + threadIdx.x;
    if (idx >= 256 * 768) return;
    int o = idx / 768, r = idx % 768;
    int tpos = r / 256, ci = r % 256;
    out[idx] = f2b(w[o * 768 + ci * 3 + tpos]);
}

__global__ void castw_kernel(const float* __restrict__ in, unsigned short* __restrict__ out, int n)
{
    int i = blockIdx.x * 256 + threadIdx.x;
    if (i < n) out[i] = f2b(in[i]);
}

// ---------------------------------------------------------------------------
// LayerNorm over dm=256 per row, fp32 in -> bf16 out. 4 rows/block (1/wave).
__global__ __launch_bounds__(256) void ln_kernel(
    const float* __restrict__ h, const float* __restrict__ g,
    const float* __restrict__ bta, unsigned short* __restrict__ out)
{
    int w = threadIdx.x >> 6, l = threadIdx.x & 63;
    int row = blockIdx.x * 4 + w;
    const float* p = h + (size_t)row * 256 + l * 4;
    float4 v = *(const float4*)p;
    float s  = v.x + v.y + v.z + v.w;
    float s2 = v.x * v.x + v.y * v.y + v.z * v.z + v.w * v.w;
#pragma unroll
    for (int m = 1; m < 64; m <<= 1) { s += __shfl_xor(s, m); s2 += __shfl_xor(s2, m); }
    float mu = s * (1.0f / 256.0f);
    float var = s2 * (1.0f / 256.0f) - mu * mu;
    float rs = rsqrtf(var + 1e-5f);
    float4 gg = *(const float4*)(g + l * 4);
    float4 bb = *(const float4*)(bta + l * 4);
    ushort4 o;
    o.x = f2b((v.x - mu) * rs * gg.x + bb.x);
    o.y = f2b((v.y - mu) * rs * gg.y + bb.y);
    o.z = f2b((v.z - mu) * rs * gg.z + bb.z);
    o.w = f2b((v.w - mu) * rs * gg.w + bb.w);
    *(ushort4*)(out + (size_t)row * 256 + l * 4) = o;
}

// ---------------------------------------------------------------------------
// bf16 GEMM: C(MxN) = A(MxK, lda) * Bt(NxK)^T, epilogue variants.
// EPI 0: +bias, store bf16.  1: +bias, GELU, store bf16.  3: +bias+res, store fp32.
template <int EPI>
__global__ __launch_bounds__(256) void gemm_bt(
    const unsigned short* __restrict__ A, const unsigned short* __restrict__ Bt,
    const float* __restrict__ bias, const float* __restrict__ res,
    void* __restrict__ Cout, int N, int K, int lda, int ldc)
{
    __shared__ unsigned short As[128 * 64];
    __shared__ unsigned short Bs[128 * 64];
    const int nbn = N >> 7;
    int bm = blockIdx.x / nbn, bn = blockIdx.x % nbn;
    int t = threadIdx.x, l = t & 63, w = t >> 6;
    int wm = w & 1, wn = w >> 1;
    f32x4 acc[4][4] = {};
    const int ktn = K >> 6;
    for (int kt = 0; kt < ktn; ++kt) {
#pragma unroll
        for (int i = 0; i < 4; ++i) {
            int off = (i * 256 + t) * 8;
            int row = off >> 6, col = off & 63;
            ushort8 va = *(const ushort8*)(A + (size_t)(bm * 128 + row) * lda + kt * 64 + col);
            *(ushort8*)(As + off) = va;
            ushort8 vb = *(const ushort8*)(Bt + (size_t)(bn * 128 + row) * K + kt * 64 + col);
            *(ushort8*)(Bs + off) = vb;
        }
        __syncthreads();
#pragma unroll
        for (int kk = 0; kk < 2; ++kk) {
            bf16x8 af[4], bfr[4];
#pragma unroll
            for (int i = 0; i < 4; ++i) {
                af[i]  = *(const bf16x8*)(As + (wm * 64 + i * 16 + (l & 15)) * 64 + kk * 32 + (l >> 4) * 8);
                bfr[i] = *(const bf16x8*)(Bs + (wn * 64 + i * 16 + (l & 15)) * 64 + kk * 32 + (l >> 4) * 8);
            }
#pragma unroll
            for (int i = 0; i < 4; ++i)
#pragma unroll
                for (int j = 0; j < 4; ++j)
                    acc[i][j] = __builtin_amdgcn_mfma_f32_16x16x32_bf16(af[i], bfr[j], acc[i][j], 0, 0, 0);
        }
        __syncthreads();
    }
    int r0 = bm * 128 + wm * 64 + (l >> 4) * 4;
    int c0 = bn * 128 + wn * 64 + (l & 15);
#pragma unroll
    for (int i = 0; i < 4; ++i) {
#pragma unroll
        for (int j = 0; j < 4; ++j) {
            int col = c0 + j * 16;
            float bb = bias[col];
#pragma unroll
            for (int q = 0; q < 4; ++q) {
                int row = r0 + i * 16 + q;
                size_t idx = (size_t)row * ldc + col;
                float v = acc[i][j][q] + bb;
                if (EPI == 0)       ((unsigned short*)Cout)[idx] = f2b(v);
                else if (EPI == 1)  ((unsigned short*)Cout)[idx] = f2b(gelu_exact(v));
                else                ((float*)Cout)[idx] = v + res[idx];
            }
        }
    }
}

// ---------------------------------------------------------------------------
// conv2 as GEMM with FUSED im2col staging. ReLU epilogue, fp32 out.
__global__ __launch_bounds__(256) void gemm_conv2(
    const unsigned short* __restrict__ h1, const unsigned short* __restrict__ Bt,
    const float* __restrict__ bias, float* __restrict__ Cout)
{
    __shared__ unsigned short As[128 * 64];
    __shared__ unsigned short Bs[128 * 64];
    int bm = blockIdx.x >> 1, bn = blockIdx.x & 1;
    int t = threadIdx.x, l = t & 63, w = t >> 6;
    int wm = w & 1, wn = w >> 1;
    f32x4 acc[4][4] = {};
    for (int kt = 0; kt < 12; ++kt) {
        int tpos = kt >> 2;          // tap 0..2
        int cbase = (kt & 3) * 64;   // channel base 0..192
#pragma unroll
        for (int i = 0; i < 4; ++i) {
            int off = (i * 256 + t) * 8;
            int row = off >> 6, col = off & 63;
            int m = bm * 128 + row;
            int b = m / 400, ll = m % 400;
            int lp = ll + tpos - 1;
            ushort8 va = (ushort8)0;
            if (lp >= 0 && lp < 400)
                va = *(const ushort8*)(h1 + ((size_t)(b * 400 + lp) * 256 + cbase + col));
            *(ushort8*)(As + off) = va;
            ushort8 vb = *(const ushort8*)(Bt + (size_t)(bn * 128 + row) * 768 + kt * 64 + col);
            *(ushort8*)(Bs + off) = vb;
        }
        __syncthreads();
#pragma unroll
        for (int kk = 0; kk < 2; ++kk) {
            bf16x8 af[4], bfr[4];
#pragma unroll
            for (int i = 0; i < 4; ++i) {
                af[i]  = *(const bf16x8*)(As + (wm * 64 + i * 16 + (l & 15)) * 64 + kk * 32 + (l >> 4) * 8);
                bfr[i] = *(const bf16x8*)(Bs + (wn * 64 + i * 16 + (l & 15)) * 64 + kk * 32 + (l >> 4) * 8);
            }
#pragma unroll
            for (int i = 0; i < 4; ++i)
#pragma unroll
                for (int j = 0; j < 4; ++j)
                    acc[i][j] = __builtin_amdgcn_mfma_f32_16x16x32_bf16(af[i], bfr[j], acc[i][j], 0, 0, 0);
        }
        __syncthreads();
    }
    int r0 = bm * 128 + wm * 64 + (l >> 4) * 4;
    int c0 = bn * 128 + wn * 64 + (l & 15);
#pragma unroll
    for (int i = 0; i < 4; ++i)
#pragma unroll
        for (int j = 0; j < 4; ++j) {
            int col = c0 + j * 16;
            float bb = bias[col];
#pragma unroll
            for (int q = 0; q < 4; ++q) {
                int row = r0 + i * 16 + q;
                Cout[(size_t)row * 256 + col] = fmaxf(acc[i][j][q] + bb, 0.0f);
            }
        }
}

// ---------------------------------------------------------------------------
// depthwise conv (k=3, pad=1, per-channel over L) + GELU; bf16 in/out, 2 ch/thread
__global__ __launch_bounds__(256) void dwconv_kernel(
    const unsigned short* __restrict__ xp, const float* __restrict__ w,
    const float* __restrict__ bias, unsigned short* __restrict__ out)
{
    int bl = blockIdx.x; int b = bl / 400, l = bl % 400;
    int t = threadIdx.x;
    int c = t * 2;
    float acc0 = bias[c], acc1 = bias[c + 1];
#pragma unroll
    for (int dt = 0; dt < 3; ++dt) {
        int lp = l + dt - 1;
        if (lp < 0 || lp >= 400) continue;
        unsigned int v = *(const unsigned int*)(xp + ((size_t)(b * 400 + lp) * 512 + c));
        acc0 += b2f((unsigned short)(v & 0xffff)) * w[c * 3 + dt];
        acc1 += b2f((unsigned short)(v >> 16)) * w[(c + 1) * 3 + dt];
    }
    unsigned int o = (unsigned int)f2b(gelu_exact(acc0)) | ((unsigned int)f2b(gelu_exact(acc1)) << 16);
    *(unsigned int*)(out + (size_t)bl * 512 + c) = o;
}

// ---------------------------------------------------------------------------
// xproj: BC(m,32) = tanh(x_conv(m,512) @ W^T(32x512) + b). 8 rows/block.
__global__ __launch_bounds__(256) void xproj_kernel(
    const unsigned short* __restrict__ xc, const unsigned short* __restrict__ w,
    const float* __restrict__ bias, float* __restrict__ BC)
{
    __shared__ unsigned short wsh[32 * 516];
    __shared__ unsigned short xs[8 * 512];
    int t = threadIdx.x;
    int m = blockIdx.x * 8;
    for (int i = t; i < 4096; i += 256) {
        int e = i * 4; int j = e / 512, k = e % 512;
        *(ushort4*)(wsh + j * 516 + k) = *(const ushort4*)(w + j * 512 + k);
    }
    for (int i = t; i < 1024; i += 256) {
        int e = i * 4;
        *(ushort4*)(xs + e) = *(const ushort4*)(xc + (size_t)m * 512 + e);
    }
    __syncthreads();
    int r = t >> 5, j = t & 31;
    const unsigned short* wr = wsh + j * 516;
    const unsigned short* xr = xs + r * 512;
    float acc = 0.0f;
#pragma unroll 8
    for (int k = 0; k < 512; k += 4) {
        ushort4 w4 = *(const ushort4*)(wr + k);
        ushort4 x4 = *(const ushort4*)(xr + k);
        acc += b2f(w4.x) * b2f(x4.x) + b2f(w4.y) * b2f(x4.y) +
               b2f(w4.z) * b2f(x4.z) + b2f(w4.w) * b2f(x4.w);
    }
    BC[(size_t)(m + r) * 32 + j] = tanhf(acc + bias[j]);
}

// ---------------------------------------------------------------------------
// Sequential SSM scan. 1 block per batch, 512 threads (thread t = channel d).
// ONE barrier per step: lds_bc and lds_red are double-buffered on the same
// parity flag; the single barrier publishes step-l reduction partials AND
// step-(l+1) B/C staging simultaneously. Race-free: pre-barrier writes touch
// only buffer cur^1 (bc) / cur (red); pre-barrier reads touch only bc[cur];
// post-barrier reads touch only red[cur], which the next iter writes at cur^1.
__global__ __launch_bounds__(512) void scan_kernel(
    const float* __restrict__ BC, const unsigned short* __restrict__ xconv,
    const unsigned short* __restrict__ gres, const float* __restrict__ Aw,
    const float* __restrict__ Dw, const float* __restrict__ sng,
    const float* __restrict__ snb, unsigned short* __restrict__ yg)
{
    __shared__ float lds_bc[2][32];
    __shared__ float lds_red[2][16];
    int b = blockIdx.x, t = threadIdx.x;
    float st[16], tA[16], g[16], bb[16];
#pragma unroll
    for (int j = 0; j < 16; ++j) {
        st[j] = 0.0f;
        tA[j] = tanhf(Aw[t * 16 + j]);
        g[j]  = sng[t * 16 + j];
        bb[j] = snb[t * 16 + j];
    }
    float Dd = Dw[t];
    const size_t base = (size_t)b * 400;
    if (t < 32) lds_bc[0][t] = BC[base * 32 + t];
    float bc_reg = (t < 32) ? BC[(base + 1) * 32 + t] : 0.0f;   // step 1
    float xt_f = b2f(xconv[base * 512 + t]);
    float gr_f = b2f(gres[base * 512 + t]);
    __syncthreads();
    int cur = 0;
    for (int l = 0; l < 400; ++l) {
        float Btv[16], Ctv[16];
#pragma unroll
        for (int j = 0; j < 16; ++j) { Btv[j] = lds_bc[cur][j]; Ctv[j] = lds_bc[cur][16 + j]; }
        if (t < 32) lds_bc[cur ^ 1][t] = bc_reg;                 // stage step l+1
        int l2 = (l + 2 < 400) ? l + 2 : 399;
        if (t < 32) bc_reg = BC[(base + l2) * 32 + t];           // prefetch step l+2
        int ln = (l + 1 < 400) ? l + 1 : 399;
        float xt = xt_f, gr = gr_f;
        xt_f = b2f(xconv[(base + ln) * 512 + t]);
        gr_f = b2f(gres[(base + ln) * 512 + t]);
        float out = xt * Dd;
#pragma unroll
        for (int j = 0; j < 16; ++j) { st[j] += Btv[j]; out += st[j] * Ctv[j]; }
        yg[(base + l) * 512 + t] = f2b(out * gr);
        float s1 = 0.0f, s2 = 0.0f;
#pragma unroll
        for (int j = 0; j < 16; ++j) { st[j] *= tA[j]; s1 += st[j]; s2 += st[j] * st[j]; }
#pragma unroll
        for (int m = 1; m < 64; m <<= 1) { s1 += __shfl_xor(s1, m); s2 += __shfl_xor(s2, m); }
        if ((t & 63) == 0) { lds_red[cur][(t >> 6) * 2] = s1; lds_red[cur][(t >> 6) * 2 + 1] = s2; }
        __syncthreads();                                          // the ONLY barrier
        float S1 = 0.0f, S2 = 0.0f;
#pragma unroll
        for (int wv = 0; wv < 8; ++wv) { S1 += lds_red[cur][wv * 2]; S2 += lds_red[cur][wv * 2 + 1]; }
        float mu = S1 * (1.0f / 8192.0f);
        float var = S2 * (1.0f / 8192.0f) - mu * mu;
        float rs = rsqrtf(var + 1e-5f);
#pragma unroll
        for (int j = 0; j < 16; ++j) st[j] = (st[j] - mu) * rs * g[j] + bb[j];
        cur ^= 1;
    }
}

// ---------------------------------------------------------------------------
// mean over L then FC (37 classes). 1 block per batch.
__global__ __launch_bounds__(256) void poolfc_kernel(
    const float* __restrict__ h, const float* __restrict__ fcw,
    const float* __restrict__ fcb, float* __restrict__ out)
{
    __shared__ float ps[256];
    int b = blockIdx.x, t = threadIdx.x;
    float s = 0.0f;
    for (int l = 0; l < 400; ++l) s += h[((size_t)b * 400 + l) * 256 + t];
    ps[t] = s * (1.0f / 400.0f);
    __syncthreads();
    if (t < 37) {
        float acc = fcb[t];
        for (int o = 0; o < 256; ++o) acc += ps[o] * fcw[t * 256 + o];
        out[b * 37 + t] = acc;
    }
}

// ---------------------------------------------------------------------------
extern "C" void kernel_launch(void* const* d_in, const int* in_sizes, int n_in,
                              void* d_out, int out_size, void* d_ws, size_t ws_size,
                              hipStream_t stream)
{
    const float* x         = (const float*)d_in[0];
    const float* conv1_w   = (const float*)d_in[1];
    const float* conv1_b   = (const float*)d_in[2];
    const float* conv2_w   = (const float*)d_in[3];
    const float* conv2_b   = (const float*)d_in[4];
    const float* ln_g      = (const float*)d_in[5];
    const float* ln_b      = (const float*)d_in[6];
    const float* inproj_w  = (const float*)d_in[7];
    const float* inproj_b  = (const float*)d_in[8];
    const float* dw_w      = (const float*)d_in[9];
    const float* dw_b      = (const float*)d_in[10];
    const float* xproj_w   = (const float*)d_in[11];
    const float* xproj_b   = (const float*)d_in[12];
    const float* A         = (const float*)d_in[13];
    const float* D         = (const float*)d_in[14];
    const float* sn_g      = (const float*)d_in[15];
    const float* sn_b      = (const float*)d_in[16];
    const float* outproj_w = (const float*)d_in[17];
    const float* outproj_b = (const float*)d_in[18];
    const float* fc_w      = (const float*)d_in[19];
    const float* fc_b      = (const float*)d_in[20];
    float* out = (float*)d_out;

    const int M = 51200; // B*L

    // Workspace layout — total 243,007,488 B.
    if (ws_size < 243007488u) return;
    char* ws = (char*)d_ws;
    float*          h    = (float*)(ws);
    unsigned short* hn   = (unsigned short*)(ws + 52428800);
    unsigned short* h1   = (unsigned short*)(ws + 52428800);
    unsigned short* xp_c = (unsigned short*)(ws + 78643200);
    unsigned short* yg   = (unsigned short*)(ws + 78643200);
    unsigned short* grs  = (unsigned short*)(ws + 131072000);
    unsigned short* xcv  = (unsigned short*)(ws + 183500800);
    float*          BC   = (float*)(ws + 235929600);
    unsigned short* wbuf = (unsigned short*)(ws + 242483200);

    // conv1 + relu -> h1 (bf16)
    conv1_kernel<<<128 * 8, 256, 0, stream>>>(x, conv1_w, conv1_b, h1);
    // conv2 weights reorder -> wbuf; conv2 GEMM (fused im2col) + relu -> h (fp32)
    reorder_w2_kernel<<<768, 256, 0, stream>>>(conv2_w, wbuf);
    gemm_conv2<<<(M / 128) * 2, 256, 0, stream>>>(h1, wbuf, conv2_b, h);

    for (int i = 0; i < 2; ++i) {
        // LN -> hn (bf16)   (overwrites h1 alias — h1 is dead by now)
        ln_kernel<<<M / 4, 256, 0, stream>>>(h, ln_g + i * 256, ln_b + i * 256, hn);
        // inproj weights -> wbuf
        castw_kernel<<<1024, 256, 0, stream>>>(inproj_w + (size_t)i * 262144, wbuf, 262144);
        // inproj first half -> xp_c (bf16)
        gemm_bt<0><<<(M / 128) * 4, 256, 0, stream>>>(hn, wbuf, inproj_b + i * 1024, nullptr,
                                                      xp_c, 512, 256, 256, 512);
        // inproj second half + GELU -> grs (bf16)
        gemm_bt<1><<<(M / 128) * 4, 256, 0, stream>>>(hn, wbuf + 131072, inproj_b + i * 1024 + 512,
                                                      nullptr, grs, 512, 256, 256, 512);
        // depthwise conv + gelu -> xcv
        dwconv_kernel<<<M, 256, 0, stream>>>(xp_c, dw_w + i * 1536, dw_b + i * 512, xcv);
        // xproj -> BC (tanh applied)
        castw_kernel<<<64, 256, 0, stream>>>(xproj_w + i * 16384, wbuf, 16384);
        xproj_kernel<<<M / 8, 256, 0, stream>>>(xcv, wbuf, xproj_b + i * 32, BC);
        // sequential scan -> yg = ssm_out * gres   (yg aliases xp_c — dead now)
        scan_kernel<<<128, 512, 0, stream>>>(BC, xcv, grs, A + i * 8192, D + i * 512,
                                             sn_g + i * 8192, sn_b + i * 8192, yg);
        // outproj + residual -> h (fp32, in place)
        castw_kernel<<<512, 256, 0, stream>>>(outproj_w + (size_t)i * 131072, wbuf, 131072);
        gemm_bt<3><<<(M / 128) * 2, 256, 0, stream>>>(yg, wbuf, outproj_b + i * 256, h, h,
                                                      256, 512, 512, 256);
    }
    // pool + fc
    poolfc_kernel<<<128, 256, 0, stream>>>(h, fc_w, fc_b, out);
}

// Round 4
// 1283.669 us; speedup vs baseline: 1.1773x; 1.0924x over previous
//
#include <hip/hip_runtime.h>
#include <hip/hip_bf16.h>
#include <math.h>

#define DEVINL __device__ __forceinline__

typedef __attribute__((ext_vector_type(4))) float  f32x4;
typedef __attribute__((ext_vector_type(8))) __bf16 bf16x8;
typedef __attribute__((ext_vector_type(8))) unsigned short ushort8;

DEVINL float b2f(unsigned short u) {
    union { unsigned int i; float f; } v; v.i = ((unsigned int)u) << 16; return v.f;
}
DEVINL unsigned short f2b(float f) {
    union { float f; unsigned int i; } v; v.f = f;
    unsigned int u = v.i;
    unsigned int r = (u + 0x7fffu + ((u >> 16) & 1u)) >> 16;
    return (unsigned short)r;
}
DEVINL float gelu_exact(float x) {
    return 0.5f * x * (1.0f + erff(x * 0.70710678118654752440f));
}

// DPP-based wave64 sum: result valid in lane 63 of each wave.
// Sequence: row_shr:1/2/4/8 then row_bcast:15, row_bcast:31 (VALU-pipe, ~8cyc/level).
template <int CTRL>
DEVINL float dpp_add(float x) {
    int xi = __builtin_bit_cast(int, x);
    int yi = __builtin_amdgcn_update_dpp(0, xi, CTRL, 0xf, 0xf, true);
    return x + __builtin_bit_cast(float, yi);
}
DEVINL float wave_sum63(float x) {
    x = dpp_add<0x111>(x);   // row_shr:1
    x = dpp_add<0x112>(x);   // row_shr:2
    x = dpp_add<0x114>(x);   // row_shr:4
    x = dpp_add<0x118>(x);   // row_shr:8
    x = dpp_add<0x142>(x);   // row_bcast:15
    x = dpp_add<0x143>(x);   // row_bcast:31
    return x;                // lane 63 holds the full 64-lane sum
}

// ---------------------------------------------------------------------------
// conv1 (Cin=8 -> 256, k=3, pad=1) + ReLU, output bf16.
__global__ __launch_bounds__(256) void conv1_kernel(
    const float* __restrict__ x, const float* __restrict__ w,
    const float* __restrict__ bias, unsigned short* __restrict__ h1)
{
    __shared__ float xs[52 * 8];
    int b = blockIdx.x >> 3, tile = blockIdx.x & 7;
    int p0 = tile * 50;
    int t = threadIdx.x;
    for (int i = t; i < 416; i += 256) {
        int p = i >> 3, c = i & 7;
        int lp = p0 + p - 1;
        xs[i] = (lp >= 0 && lp < 400) ? x[((size_t)b * 400 + lp) * 8 + c] : 0.0f;
    }
    float wr[24];
    const float4* wp = (const float4*)(w + t * 24);
#pragma unroll
    for (int i = 0; i < 6; ++i) {
        float4 v4 = wp[i];
        wr[i * 4] = v4.x; wr[i * 4 + 1] = v4.y; wr[i * 4 + 2] = v4.z; wr[i * 4 + 3] = v4.w;
    }
    float bs = bias[t];
    __syncthreads();
#pragma unroll 2
    for (int p = 0; p < 50; ++p) {
        float acc = bs;
#pragma unroll
        for (int dt = 0; dt < 3; ++dt)
#pragma unroll
            for (int c = 0; c < 8; ++c)
                acc += xs[(p + dt) * 8 + c] * wr[c * 3 + dt];
        h1[((size_t)b * 400 + p0 + p) * 256 + t] = f2b(fmaxf(acc, 0.0f));
    }
}

// conv2 weight reorder (o, ci, t) -> w2r[o, t*256+ci] bf16
__global__ void reorder_w2_kernel(const float* __restrict__ w, unsigned short* __restrict__ out)
{
    int idx = blockIdx.x * 256 + threadIdx.x;
    if (idx >= 256 * 768) return;
    int o = idx / 768, r = idx % 768;
    int tpos = r / 256, ci = r % 256;
    out[idx] = f2b(w[o * 768 + ci * 3 + tpos]);
}

__global__ void castw_kernel(const float* __restrict__ in, unsigned short* __restrict__ out, int n)
{
    int i = blockIdx.x * 256 + threadIdx.x;
    if (i < n) out[i] = f2b(in[i]);
}

// ---------------------------------------------------------------------------
// LayerNorm over dm=256 per row, fp32 in -> bf16 out. 4 rows/block (1/wave).
__global__ __launch_bounds__(256) void ln_kernel(
    const float* __restrict__ h, const float* __restrict__ g,
    const float* __restrict__ bta, unsigned short* __restrict__ out)
{
    int w = threadIdx.x >> 6, l = threadIdx.x & 63;
    int row = blockIdx.x * 4 + w;
    const float* p = h + (size_t)row * 256 + l * 4;
    float4 v = *(const float4*)p;
    float s  = v.x + v.y + v.z + v.w;
    float s2 = v.x * v.x + v.y * v.y + v.z * v.z + v.w * v.w;
#pragma unroll
    for (int m = 1; m < 64; m <<= 1) { s += __shfl_xor(s, m); s2 += __shfl_xor(s2, m); }
    float mu = s * (1.0f / 256.0f);
    float var = s2 * (1.0f / 256.0f) - mu * mu;
    float rs = rsqrtf(var + 1e-5f);
    float4 gg = *(const float4*)(g + l * 4);
    float4 bb = *(const float4*)(bta + l * 4);
    ushort4 o;
    o.x = f2b((v.x - mu) * rs * gg.x + bb.x);
    o.y = f2b((v.y - mu) * rs * gg.y + bb.y);
    o.z = f2b((v.z - mu) * rs * gg.z + bb.z);
    o.w = f2b((v.w - mu) * rs * gg.w + bb.w);
    *(ushort4*)(out + (size_t)row * 256 + l * 4) = o;
}

// ---------------------------------------------------------------------------
// bf16 GEMM: C(MxN) = A(MxK, lda) * Bt(NxK)^T, epilogue variants.
template <int EPI>
__global__ __launch_bounds__(256) void gemm_bt(
    const unsigned short* __restrict__ A, const unsigned short* __restrict__ Bt,
    const float* __restrict__ bias, const float* __restrict__ res,
    void* __restrict__ Cout, int N, int K, int lda, int ldc)
{
    __shared__ unsigned short As[128 * 64];
    __shared__ unsigned short Bs[128 * 64];
    const int nbn = N >> 7;
    int bm = blockIdx.x / nbn, bn = blockIdx.x % nbn;
    int t = threadIdx.x, l = t & 63, w = t >> 6;
    int wm = w & 1, wn = w >> 1;
    f32x4 acc[4][4] = {};
    const int ktn = K >> 6;
    for (int kt = 0; kt < ktn; ++kt) {
#pragma unroll
        for (int i = 0; i < 4; ++i) {
            int off = (i * 256 + t) * 8;
            int row = off >> 6, col = off & 63;
            ushort8 va = *(const ushort8*)(A + (size_t)(bm * 128 + row) * lda + kt * 64 + col);
            *(ushort8*)(As + off) = va;
            ushort8 vb = *(const ushort8*)(Bt + (size_t)(bn * 128 + row) * K + kt * 64 + col);
            *(ushort8*)(Bs + off) = vb;
        }
        __syncthreads();
#pragma unroll
        for (int kk = 0; kk < 2; ++kk) {
            bf16x8 af[4], bfr[4];
#pragma unroll
            for (int i = 0; i < 4; ++i) {
                af[i]  = *(const bf16x8*)(As + (wm * 64 + i * 16 + (l & 15)) * 64 + kk * 32 + (l >> 4) * 8);
                bfr[i] = *(const bf16x8*)(Bs + (wn * 64 + i * 16 + (l & 15)) * 64 + kk * 32 + (l >> 4) * 8);
            }
#pragma unroll
            for (int i = 0; i < 4; ++i)
#pragma unroll
                for (int j = 0; j < 4; ++j)
                    acc[i][j] = __builtin_amdgcn_mfma_f32_16x16x32_bf16(af[i], bfr[j], acc[i][j], 0, 0, 0);
        }
        __syncthreads();
    }
    int r0 = bm * 128 + wm * 64 + (l >> 4) * 4;
    int c0 = bn * 128 + wn * 64 + (l & 15);
#pragma unroll
    for (int i = 0; i < 4; ++i) {
#pragma unroll
        for (int j = 0; j < 4; ++j) {
            int col = c0 + j * 16;
            float bb = bias[col];
#pragma unroll
            for (int q = 0; q < 4; ++q) {
                int row = r0 + i * 16 + q;
                size_t idx = (size_t)row * ldc + col;
                float v = acc[i][j][q] + bb;
                if (EPI == 0)       ((unsigned short*)Cout)[idx] = f2b(v);
                else if (EPI == 1)  ((unsigned short*)Cout)[idx] = f2b(gelu_exact(v));
                else                ((float*)Cout)[idx] = v + res[idx];
            }
        }
    }
}

// ---------------------------------------------------------------------------
// conv2 as GEMM with FUSED im2col staging. ReLU epilogue, fp32 out.
__global__ __launch_bounds__(256) void gemm_conv2(
    const unsigned short* __restrict__ h1, const unsigned short* __restrict__ Bt,
    const float* __restrict__ bias, float* __restrict__ Cout)
{
    __shared__ unsigned short As[128 * 64];
    __shared__ unsigned short Bs[128 * 64];
    int bm = blockIdx.x >> 1, bn = blockIdx.x & 1;
    int t = threadIdx.x, l = t & 63, w = t >> 6;
    int wm = w & 1, wn = w >> 1;
    f32x4 acc[4][4] = {};
    for (int kt = 0; kt < 12; ++kt) {
        int tpos = kt >> 2;
        int cbase = (kt & 3) * 64;
#pragma unroll
        for (int i = 0; i < 4; ++i) {
            int off = (i * 256 + t) * 8;
            int row = off >> 6, col = off & 63;
            int m = bm * 128 + row;
            int b = m / 400, ll = m % 400;
            int lp = ll + tpos - 1;
            ushort8 va = (ushort8)0;
            if (lp >= 0 && lp < 400)
                va = *(const ushort8*)(h1 + ((size_t)(b * 400 + lp) * 256 + cbase + col));
            *(ushort8*)(As + off) = va;
            ushort8 vb = *(const ushort8*)(Bt + (size_t)(bn * 128 + row) * 768 + kt * 64 + col);
            *(ushort8*)(Bs + off) = vb;
        }
        __syncthreads();
#pragma unroll
        for (int kk = 0; kk < 2; ++kk) {
            bf16x8 af[4], bfr[4];
#pragma unroll
            for (int i = 0; i < 4; ++i) {
                af[i]  = *(const bf16x8*)(As + (wm * 64 + i * 16 + (l & 15)) * 64 + kk * 32 + (l >> 4) * 8);
                bfr[i] = *(const bf16x8*)(Bs + (wn * 64 + i * 16 + (l & 15)) * 64 + kk * 32 + (l >> 4) * 8);
            }
#pragma unroll
            for (int i = 0; i < 4; ++i)
#pragma unroll
                for (int j = 0; j < 4; ++j)
                    acc[i][j] = __builtin_amdgcn_mfma_f32_16x16x32_bf16(af[i], bfr[j], acc[i][j], 0, 0, 0);
        }
        __syncthreads();
    }
    int r0 = bm * 128 + wm * 64 + (l >> 4) * 4;
    int c0 = bn * 128 + wn * 64 + (l & 15);
#pragma unroll
    for (int i = 0; i < 4; ++i)
#pragma unroll
        for (int j = 0; j < 4; ++j) {
            int col = c0 + j * 16;
            float bb = bias[col];
#pragma unroll
            for (int q = 0; q < 4; ++q) {
                int row = r0 + i * 16 + q;
                Cout[(size_t)row * 256 + col] = fmaxf(acc[i][j][q] + bb, 0.0f);
            }
        }
}

// ---------------------------------------------------------------------------
// depthwise conv (k=3, pad=1, per-channel over L) + GELU; bf16 in/out, 2 ch/thread
__global__ __launch_bounds__(256) void dwconv_kernel(
    const unsigned short* __restrict__ xp, const float* __restrict__ w,
    const float* __restrict__ bias, unsigned short* __restrict__ out)
{
    int bl = blockIdx.x; int b = bl / 400, l = bl % 400;
    int t = threadIdx.x;
    int c = t * 2;
    float acc0 = bias[c], acc1 = bias[c + 1];
#pragma unroll
    for (int dt = 0; dt < 3; ++dt) {
        int lp = l + dt - 1;
        if (lp < 0 || lp >= 400) continue;
        unsigned int v = *(const unsigned int*)(xp + ((size_t)(b * 400 + lp) * 512 + c));
        acc0 += b2f((unsigned short)(v & 0xffff)) * w[c * 3 + dt];
        acc1 += b2f((unsigned short)(v >> 16)) * w[(c + 1) * 3 + dt];
    }
    unsigned int o = (unsigned int)f2b(gelu_exact(acc0)) | ((unsigned int)f2b(gelu_exact(acc1)) << 16);
    *(unsigned int*)(out + (size_t)bl * 512 + c) = o;
}

// ---------------------------------------------------------------------------
// xproj: BC(m,32) = tanh(x_conv(m,512) @ W^T(32x512) + b). 8 rows/block.
__global__ __launch_bounds__(256) void xproj_kernel(
    const unsigned short* __restrict__ xc, const unsigned short* __restrict__ w,
    const float* __restrict__ bias, float* __restrict__ BC)
{
    __shared__ unsigned short wsh[32 * 516];
    __shared__ unsigned short xs[8 * 512];
    int t = threadIdx.x;
    int m = blockIdx.x * 8;
    for (int i = t; i < 4096; i += 256) {
        int e = i * 4; int j = e / 512, k = e % 512;
        *(ushort4*)(wsh + j * 516 + k) = *(const ushort4*)(w + j * 512 + k);
    }
    for (int i = t; i < 1024; i += 256) {
        int e = i * 4;
        *(ushort4*)(xs + e) = *(const ushort4*)(xc + (size_t)m * 512 + e);
    }
    __syncthreads();
    int r = t >> 5, j = t & 31;
    const unsigned short* wr = wsh + j * 516;
    const unsigned short* xr = xs + r * 512;
    float acc = 0.0f;
#pragma unroll 8
    for (int k = 0; k < 512; k += 4) {
        ushort4 w4 = *(const ushort4*)(wr + k);
        ushort4 x4 = *(const ushort4*)(xr + k);
        acc += b2f(w4.x) * b2f(x4.x) + b2f(w4.y) * b2f(x4.y) +
               b2f(w4.z) * b2f(x4.z) + b2f(w4.w) * b2f(x4.w);
    }
    BC[(size_t)(m + r) * 32 + j] = tanhf(acc + bias[j]);
}

// ---------------------------------------------------------------------------
// Sequential SSM scan. 1 block per batch, 512 threads (thread t = channel d).
// One barrier per step; wave reduce via DPP (VALU pipe) instead of ds-shuffles.
__global__ __launch_bounds__(512) void scan_kernel(
    const float* __restrict__ BC, const unsigned short* __restrict__ xconv,
    const unsigned short* __restrict__ gres, const float* __restrict__ Aw,
    const float* __restrict__ Dw, const float* __restrict__ sng,
    const float* __restrict__ snb, unsigned short* __restrict__ yg)
{
    __shared__ __align__(16) float lds_bc[2][32];
    __shared__ __align__(16) float lds_s1[2][8];
    __shared__ __align__(16) float lds_s2[2][8];
    int b = blockIdx.x, t = threadIdx.x;
    float st[16], tA[16], g[16], bb[16];
#pragma unroll
    for (int j = 0; j < 16; ++j) {
        st[j] = 0.0f;
        tA[j] = tanhf(Aw[t * 16 + j]);
        g[j]  = sng[t * 16 + j];
        bb[j] = snb[t * 16 + j];
    }
    float Dd = Dw[t];
    const size_t base = (size_t)b * 400;
    if (t < 32) lds_bc[0][t] = BC[base * 32 + t];
    float bc_reg = (t < 32) ? BC[(base + 1) * 32 + t] : 0.0f;   // step 1
    float xt_f = b2f(xconv[base * 512 + t]);
    float gr_f = b2f(gres[base * 512 + t]);
    __syncthreads();
    int cur = 0;
    for (int l = 0; l < 400; ++l) {
        float Btv[16], Ctv[16];
#pragma unroll
        for (int q = 0; q < 4; ++q) {
            float4 bv = *(const float4*)&lds_bc[cur][q * 4];
            float4 cv = *(const float4*)&lds_bc[cur][16 + q * 4];
            Btv[q*4] = bv.x; Btv[q*4+1] = bv.y; Btv[q*4+2] = bv.z; Btv[q*4+3] = bv.w;
            Ctv[q*4] = cv.x; Ctv[q*4+1] = cv.y; Ctv[q*4+2] = cv.z; Ctv[q*4+3] = cv.w;
        }
        if (t < 32) lds_bc[cur ^ 1][t] = bc_reg;                 // stage step l+1
        int l2 = (l + 2 < 400) ? l + 2 : 399;
        if (t < 32) bc_reg = BC[(base + l2) * 32 + t];           // prefetch step l+2
        int ln = (l + 1 < 400) ? l + 1 : 399;
        float xt = xt_f, gr = gr_f;
        xt_f = b2f(xconv[(base + ln) * 512 + t]);
        gr_f = b2f(gres[(base + ln) * 512 + t]);
        // state += B; out = state.C + x*D (paired accumulators for ILP)
        float oa = xt * Dd, ob = 0.0f;
#pragma unroll
        for (int j = 0; j < 16; j += 2) {
            st[j]     += Btv[j];     oa += st[j]     * Ctv[j];
            st[j + 1] += Btv[j + 1]; ob += st[j + 1] * Ctv[j + 1];
        }
        yg[(base + l) * 512 + t] = f2b((oa + ob) * gr);
        // state *= tA; partial sums (2 accumulators each)
        float a0 = 0.f, a1 = 0.f, q0 = 0.f, q1 = 0.f;
#pragma unroll
        for (int j = 0; j < 16; j += 2) {
            st[j]     *= tA[j];     a0 += st[j];     q0 += st[j]     * st[j];
            st[j + 1] *= tA[j + 1]; a1 += st[j + 1]; q1 += st[j + 1] * st[j + 1];
        }
        float s1 = wave_sum63(a0 + a1);
        float s2 = wave_sum63(q0 + q1);
        if ((t & 63) == 63) { int wv = t >> 6; lds_s1[cur][wv] = s1; lds_s2[cur][wv] = s2; }
        __syncthreads();                                          // the ONLY barrier
        float4 p0 = *(const float4*)&lds_s1[cur][0];
        float4 p1 = *(const float4*)&lds_s1[cur][4];
        float4 r0 = *(const float4*)&lds_s2[cur][0];
        float4 r1 = *(const float4*)&lds_s2[cur][4];
        float S1 = ((p0.x + p0.y) + (p0.z + p0.w)) + ((p1.x + p1.y) + (p1.z + p1.w));
        float S2 = ((r0.x + r0.y) + (r0.z + r0.w)) + ((r1.x + r1.y) + (r1.z + r1.w));
        float mu = S1 * (1.0f / 8192.0f);
        float var = S2 * (1.0f / 8192.0f) - mu * mu;
        float rs = rsqrtf(var + 1e-5f);
#pragma unroll
        for (int j = 0; j < 16; ++j) st[j] = (st[j] - mu) * rs * g[j] + bb[j];
        cur ^= 1;
    }
}

// ---------------------------------------------------------------------------
// mean over L then FC (37 classes). 1 block per batch.
__global__ __launch_bounds__(256) void poolfc_kernel(
    const float* __restrict__ h, const float* __restrict__ fcw,
    const float* __restrict__ fcb, float* __restrict__ out)
{
    __shared__ float ps[256];
    int b = blockIdx.x, t = threadIdx.x;
    float s = 0.0f;
    for (int l = 0; l < 400; ++l) s += h[((size_t)b * 400 + l) * 256 + t];
    ps[t] = s * (1.0f / 400.0f);
    __syncthreads();
    if (t < 37) {
        float acc = fcb[t];
        for (int o = 0; o < 256; ++o) acc += ps[o] * fcw[t * 256 + o];
        out[b * 37 + t] = acc;
    }
}

// ---------------------------------------------------------------------------
extern "C" void kernel_launch(void* const* d_in, const int* in_sizes, int n_in,
                              void* d_out, int out_size, void* d_ws, size_t ws_size,
                              hipStream_t stream)
{
    const float* x         = (const float*)d_in[0];
    const float* conv1_w   = (const float*)d_in[1];
    const float* conv1_b   = (const float*)d_in[2];
    const float* conv2_w   = (const float*)d_in[3];
    const float* conv2_b   = (const float*)d_in[4];
    const float* ln_g      = (const float*)d_in[5];
    const float* ln_b      = (const float*)d_in[6];
    const float* inproj_w  = (const float*)d_in[7];
    const float* inproj_b  = (const float*)d_in[8];
    const float* dw_w      = (const float*)d_in[9];
    const float* dw_b      = (const float*)d_in[10];
    const float* xproj_w   = (const float*)d_in[11];
    const float* xproj_b   = (const float*)d_in[12];
    const float* A         = (const float*)d_in[13];
    const float* D         = (const float*)d_in[14];
    const float* sn_g      = (const float*)d_in[15];
    const float* sn_b      = (const float*)d_in[16];
    const float* outproj_w = (const float*)d_in[17];
    const float* outproj_b = (const float*)d_in[18];
    const float* fc_w      = (const float*)d_in[19];
    const float* fc_b      = (const float*)d_in[20];
    float* out = (float*)d_out;

    const int M = 51200; // B*L

    if (ws_size < 243007488u) return;
    char* ws = (char*)d_ws;
    float*          h    = (float*)(ws);
    unsigned short* hn   = (unsigned short*)(ws + 52428800);
    unsigned short* h1   = (unsigned short*)(ws + 52428800);
    unsigned short* xp_c = (unsigned short*)(ws + 78643200);
    unsigned short* yg   = (unsigned short*)(ws + 78643200);
    unsigned short* grs  = (unsigned short*)(ws + 131072000);
    unsigned short* xcv  = (unsigned short*)(ws + 183500800);
    float*          BC   = (float*)(ws + 235929600);
    unsigned short* wbuf = (unsigned short*)(ws + 242483200);

    conv1_kernel<<<128 * 8, 256, 0, stream>>>(x, conv1_w, conv1_b, h1);
    reorder_w2_kernel<<<768, 256, 0, stream>>>(conv2_w, wbuf);
    gemm_conv2<<<(M / 128) * 2, 256, 0, stream>>>(h1, wbuf, conv2_b, h);

    for (int i = 0; i < 2; ++i) {
        ln_kernel<<<M / 4, 256, 0, stream>>>(h, ln_g + i * 256, ln_b + i * 256, hn);
        castw_kernel<<<1024, 256, 0, stream>>>(inproj_w + (size_t)i * 262144, wbuf, 262144);
        gemm_bt<0><<<(M / 128) * 4, 256, 0, stream>>>(hn, wbuf, inproj_b + i * 1024, nullptr,
                                                      xp_c, 512, 256, 256, 512);
        gemm_bt<1><<<(M / 128) * 4, 256, 0, stream>>>(hn, wbuf + 131072, inproj_b + i * 1024 + 512,
                                                      nullptr, grs, 512, 256, 256, 512);
        dwconv_kernel<<<M, 256, 0, stream>>>(xp_c, dw_w + i * 1536, dw_b + i * 512, xcv);
        castw_kernel<<<64, 256, 0, stream>>>(xproj_w + i * 16384, wbuf, 16384);
        xproj_kernel<<<M / 8, 256, 0, stream>>>(xcv, wbuf, xproj_b + i * 32, BC);
        scan_kernel<<<128, 512, 0, stream>>>(BC, xcv, grs, A + i * 8192, D + i * 512,
                                             sn_g + i * 8192, sn_b + i * 8192, yg);
        castw_kernel<<<512, 256, 0, stream>>>(outproj_w + (size_t)i * 131072, wbuf, 131072);
        gemm_bt<3><<<(M / 128) * 2, 256, 0, stream>>>(yg, wbuf, outproj_b + i * 256, h, h,
                                                      256, 512, 512, 256);
    }
    poolfc_kernel<<<128, 256, 0, stream>>>(h, fc_w, fc_b, out);
}

// Round 5
// 1252.112 us; speedup vs baseline: 1.2069x; 1.0252x over previous
//
#include <hip/hip_runtime.h>
#include <hip/hip_bf16.h>
#include <math.h>

#define DEVINL __device__ __forceinline__

typedef __attribute__((ext_vector_type(4))) float  f32x4;
typedef __attribute__((ext_vector_type(8))) __bf16 bf16x8;
typedef __attribute__((ext_vector_type(8))) unsigned short ushort8;

DEVINL float b2f(unsigned short u) {
    union { unsigned int i; float f; } v; v.i = ((unsigned int)u) << 16; return v.f;
}
DEVINL unsigned short f2b(float f) {
    union { float f; unsigned int i; } v; v.f = f;
    unsigned int u = v.i;
    unsigned int r = (u + 0x7fffu + ((u >> 16) & 1u)) >> 16;
    return (unsigned short)r;
}
DEVINL float gelu_exact(float x) {
    return 0.5f * x * (1.0f + erff(x * 0.70710678118654752440f));
}

// DPP-based wave64 sum: result valid in lane 63 of each wave.
template <int CTRL>
DEVINL float dpp_add(float x) {
    int xi = __builtin_bit_cast(int, x);
    int yi = __builtin_amdgcn_update_dpp(0, xi, CTRL, 0xf, 0xf, true);
    return x + __builtin_bit_cast(float, yi);
}
DEVINL float wave_sum63(float x) {
    x = dpp_add<0x111>(x);   // row_shr:1
    x = dpp_add<0x112>(x);   // row_shr:2
    x = dpp_add<0x114>(x);   // row_shr:4
    x = dpp_add<0x118>(x);   // row_shr:8
    x = dpp_add<0x142>(x);   // row_bcast:15
    x = dpp_add<0x143>(x);   // row_bcast:31
    return x;                // lane 63 holds the full 64-lane sum
}

// ---------------------------------------------------------------------------
// conv1 (Cin=8 -> 256, k=3, pad=1) + ReLU, output bf16.
__global__ __launch_bounds__(256) void conv1_kernel(
    const float* __restrict__ x, const float* __restrict__ w,
    const float* __restrict__ bias, unsigned short* __restrict__ h1)
{
    __shared__ float xs[52 * 8];
    int b = blockIdx.x >> 3, tile = blockIdx.x & 7;
    int p0 = tile * 50;
    int t = threadIdx.x;
    for (int i = t; i < 416; i += 256) {
        int p = i >> 3, c = i & 7;
        int lp = p0 + p - 1;
        xs[i] = (lp >= 0 && lp < 400) ? x[((size_t)b * 400 + lp) * 8 + c] : 0.0f;
    }
    float wr[24];
    const float4* wp = (const float4*)(w + t * 24);
#pragma unroll
    for (int i = 0; i < 6; ++i) {
        float4 v4 = wp[i];
        wr[i * 4] = v4.x; wr[i * 4 + 1] = v4.y; wr[i * 4 + 2] = v4.z; wr[i * 4 + 3] = v4.w;
    }
    float bs = bias[t];
    __syncthreads();
#pragma unroll 2
    for (int p = 0; p < 50; ++p) {
        float acc = bs;
#pragma unroll
        for (int dt = 0; dt < 3; ++dt)
#pragma unroll
            for (int c = 0; c < 8; ++c)
                acc += xs[(p + dt) * 8 + c] * wr[c * 3 + dt];
        h1[((size_t)b * 400 + p0 + p) * 256 + t] = f2b(fmaxf(acc, 0.0f));
    }
}

// conv2 weight reorder (o, ci, t) -> w2r[o, t*256+ci] bf16
__global__ void reorder_w2_kernel(const float* __restrict__ w, unsigned short* __restrict__ out)
{
    int idx = blockIdx.x * 256 + threadIdx.x;
    if (idx >= 256 * 768) return;
    int o = idx / 768, r = idx % 768;
    int tpos = r / 256, ci = r % 256;
    out[idx] = f2b(w[o * 768 + ci * 3 + tpos]);
}

__global__ void castw_kernel(const float* __restrict__ in, unsigned short* __restrict__ out, int n)
{
    int i = blockIdx.x * 256 + threadIdx.x;
    if (i < n) out[i] = f2b(in[i]);
}

// ---------------------------------------------------------------------------
// LayerNorm over dm=256 per row, fp32 in -> bf16 out. 4 rows/block (1/wave).
__global__ __launch_bounds__(256) void ln_kernel(
    const float* __restrict__ h, const float* __restrict__ g,
    const float* __restrict__ bta, unsigned short* __restrict__ out)
{
    int w = threadIdx.x >> 6, l = threadIdx.x & 63;
    int row = blockIdx.x * 4 + w;
    const float* p = h + (size_t)row * 256 + l * 4;
    float4 v = *(const float4*)p;
    float s  = v.x + v.y + v.z + v.w;
    float s2 = v.x * v.x + v.y * v.y + v.z * v.z + v.w * v.w;
#pragma unroll
    for (int m = 1; m < 64; m <<= 1) { s += __shfl_xor(s, m); s2 += __shfl_xor(s2, m); }
    float mu = s * (1.0f / 256.0f);
    float var = s2 * (1.0f / 256.0f) - mu * mu;
    float rs = rsqrtf(var + 1e-5f);
    float4 gg = *(const float4*)(g + l * 4);
    float4 bb = *(const float4*)(bta + l * 4);
    ushort4 o;
    o.x = f2b((v.x - mu) * rs * gg.x + bb.x);
    o.y = f2b((v.y - mu) * rs * gg.y + bb.y);
    o.z = f2b((v.z - mu) * rs * gg.z + bb.z);
    o.w = f2b((v.w - mu) * rs * gg.w + bb.w);
    *(ushort4*)(out + (size_t)row * 256 + l * 4) = o;
}

// ---------------------------------------------------------------------------
// bf16 GEMM: C(MxN) = A(MxK, lda) * Bt(NxK)^T, epilogue variants.
template <int EPI>
__global__ __launch_bounds__(256) void gemm_bt(
    const unsigned short* __restrict__ A, const unsigned short* __restrict__ Bt,
    const float* __restrict__ bias, const float* __restrict__ res,
    void* __restrict__ Cout, int N, int K, int lda, int ldc)
{
    __shared__ unsigned short As[128 * 64];
    __shared__ unsigned short Bs[128 * 64];
    const int nbn = N >> 7;
    int bm = blockIdx.x / nbn, bn = blockIdx.x % nbn;
    int t = threadIdx.x, l = t & 63, w = t >> 6;
    int wm = w & 1, wn = w >> 1;
    f32x4 acc[4][4] = {};
    const int ktn = K >> 6;
    for (int kt = 0; kt < ktn; ++kt) {
#pragma unroll
        for (int i = 0; i < 4; ++i) {
            int off = (i * 256 + t) * 8;
            int row = off >> 6, col = off & 63;
            ushort8 va = *(const ushort8*)(A + (size_t)(bm * 128 + row) * lda + kt * 64 + col);
            *(ushort8*)(As + off) = va;
            ushort8 vb = *(const ushort8*)(Bt + (size_t)(bn * 128 + row) * K + kt * 64 + col);
            *(ushort8*)(Bs + off) = vb;
        }
        __syncthreads();
#pragma unroll
        for (int kk = 0; kk < 2; ++kk) {
            bf16x8 af[4], bfr[4];
#pragma unroll
            for (int i = 0; i < 4; ++i) {
                af[i]  = *(const bf16x8*)(As + (wm * 64 + i * 16 + (l & 15)) * 64 + kk * 32 + (l >> 4) * 8);
                bfr[i] = *(const bf16x8*)(Bs + (wn * 64 + i * 16 + (l & 15)) * 64 + kk * 32 + (l >> 4) * 8);
            }
#pragma unroll
            for (int i = 0; i < 4; ++i)
#pragma unroll
                for (int j = 0; j < 4; ++j)
                    acc[i][j] = __builtin_amdgcn_mfma_f32_16x16x32_bf16(af[i], bfr[j], acc[i][j], 0, 0, 0);
        }
        __syncthreads();
    }
    int r0 = bm * 128 + wm * 64 + (l >> 4) * 4;
    int c0 = bn * 128 + wn * 64 + (l & 15);
#pragma unroll
    for (int i = 0; i < 4; ++i) {
#pragma unroll
        for (int j = 0; j < 4; ++j) {
            int col = c0 + j * 16;
            float bb = bias[col];
#pragma unroll
            for (int q = 0; q < 4; ++q) {
                int row = r0 + i * 16 + q;
                size_t idx = (size_t)row * ldc + col;
                float v = acc[i][j][q] + bb;
                if (EPI == 0)       ((unsigned short*)Cout)[idx] = f2b(v);
                else if (EPI == 1)  ((unsigned short*)Cout)[idx] = f2b(gelu_exact(v));
                else                ((float*)Cout)[idx] = v + res[idx];
            }
        }
    }
}

// ---------------------------------------------------------------------------
// conv2 as GEMM with FUSED im2col staging. ReLU epilogue, fp32 out.
__global__ __launch_bounds__(256) void gemm_conv2(
    const unsigned short* __restrict__ h1, const unsigned short* __restrict__ Bt,
    const float* __restrict__ bias, float* __restrict__ Cout)
{
    __shared__ unsigned short As[128 * 64];
    __shared__ unsigned short Bs[128 * 64];
    int bm = blockIdx.x >> 1, bn = blockIdx.x & 1;
    int t = threadIdx.x, l = t & 63, w = t >> 6;
    int wm = w & 1, wn = w >> 1;
    f32x4 acc[4][4] = {};
    for (int kt = 0; kt < 12; ++kt) {
        int tpos = kt >> 2;
        int cbase = (kt & 3) * 64;
#pragma unroll
        for (int i = 0; i < 4; ++i) {
            int off = (i * 256 + t) * 8;
            int row = off >> 6, col = off & 63;
            int m = bm * 128 + row;
            int b = m / 400, ll = m % 400;
            int lp = ll + tpos - 1;
            ushort8 va = (ushort8)0;
            if (lp >= 0 && lp < 400)
                va = *(const ushort8*)(h1 + ((size_t)(b * 400 + lp) * 256 + cbase + col));
            *(ushort8*)(As + off) = va;
            ushort8 vb = *(const ushort8*)(Bt + (size_t)(bn * 128 + row) * 768 + kt * 64 + col);
            *(ushort8*)(Bs + off) = vb;
        }
        __syncthreads();
#pragma unroll
        for (int kk = 0; kk < 2; ++kk) {
            bf16x8 af[4], bfr[4];
#pragma unroll
            for (int i = 0; i < 4; ++i) {
                af[i]  = *(const bf16x8*)(As + (wm * 64 + i * 16 + (l & 15)) * 64 + kk * 32 + (l >> 4) * 8);
                bfr[i] = *(const bf16x8*)(Bs + (wn * 64 + i * 16 + (l & 15)) * 64 + kk * 32 + (l >> 4) * 8);
            }
#pragma unroll
            for (int i = 0; i < 4; ++i)
#pragma unroll
                for (int j = 0; j < 4; ++j)
                    acc[i][j] = __builtin_amdgcn_mfma_f32_16x16x32_bf16(af[i], bfr[j], acc[i][j], 0, 0, 0);
        }
        __syncthreads();
    }
    int r0 = bm * 128 + wm * 64 + (l >> 4) * 4;
    int c0 = bn * 128 + wn * 64 + (l & 15);
#pragma unroll
    for (int i = 0; i < 4; ++i)
#pragma unroll
        for (int j = 0; j < 4; ++j) {
            int col = c0 + j * 16;
            float bb = bias[col];
#pragma unroll
            for (int q = 0; q < 4; ++q) {
                int row = r0 + i * 16 + q;
                Cout[(size_t)row * 256 + col] = fmaxf(acc[i][j][q] + bb, 0.0f);
            }
        }
}

// ---------------------------------------------------------------------------
// depthwise conv (k=3, pad=1) + GELU; bf16 in/out.
// 1024 blocks = 128 b x 8 tiles of 50 positions; thread = channel pair,
// register-sliding window over L (1.04 loads/output instead of 3).
__global__ __launch_bounds__(256) void dwconv_kernel(
    const unsigned short* __restrict__ xp, const float* __restrict__ w,
    const float* __restrict__ bias, unsigned short* __restrict__ out)
{
    int b = blockIdx.x >> 3, tile = blockIdx.x & 7;
    int p0 = tile * 50;
    int t = threadIdx.x;
    int c = t * 2;
    float w00 = w[c * 3], w01 = w[c * 3 + 1], w02 = w[c * 3 + 2];
    float w10 = w[c * 3 + 3], w11 = w[c * 3 + 4], w12 = w[c * 3 + 5];
    float b0 = bias[c], b1 = bias[c + 1];
    const size_t rowb = (size_t)b * 400;
    int l = p0;
    unsigned int r0 = (l - 1 >= 0) ? *(const unsigned int*)(xp + (rowb + l - 1) * 512 + c) : 0u;
    unsigned int r1 = *(const unsigned int*)(xp + (rowb + l) * 512 + c);
    for (int q = 0; q < 50; ++q, ++l) {
        unsigned int r2 = (l + 1 < 400) ? *(const unsigned int*)(xp + (rowb + l + 1) * 512 + c) : 0u;
        float a0 = b0 + b2f((unsigned short)(r0 & 0xffff)) * w00
                      + b2f((unsigned short)(r1 & 0xffff)) * w01
                      + b2f((unsigned short)(r2 & 0xffff)) * w02;
        float a1 = b1 + b2f((unsigned short)(r0 >> 16)) * w10
                      + b2f((unsigned short)(r1 >> 16)) * w11
                      + b2f((unsigned short)(r2 >> 16)) * w12;
        unsigned int o = (unsigned int)f2b(gelu_exact(a0)) | ((unsigned int)f2b(gelu_exact(a1)) << 16);
        *(unsigned int*)(out + (rowb + l) * 512 + c) = o;
        r0 = r1; r1 = r2;
    }
}

// ---------------------------------------------------------------------------
// xproj: BC(m,32) = tanh(x_conv(m,512) @ W^T(32x512) + b). 8 rows/block.
__global__ __launch_bounds__(256) void xproj_kernel(
    const unsigned short* __restrict__ xc, const unsigned short* __restrict__ w,
    const float* __restrict__ bias, float* __restrict__ BC)
{
    __shared__ unsigned short wsh[32 * 516];
    __shared__ unsigned short xs[8 * 512];
    int t = threadIdx.x;
    int m = blockIdx.x * 8;
    for (int i = t; i < 4096; i += 256) {
        int e = i * 4; int j = e / 512, k = e % 512;
        *(ushort4*)(wsh + j * 516 + k) = *(const ushort4*)(w + j * 512 + k);
    }
    for (int i = t; i < 1024; i += 256) {
        int e = i * 4;
        *(ushort4*)(xs + e) = *(const ushort4*)(xc + (size_t)m * 512 + e);
    }
    __syncthreads();
    int r = t >> 5, j = t & 31;
    const unsigned short* wr = wsh + j * 516;
    const unsigned short* xr = xs + r * 512;
    float acc = 0.0f;
#pragma unroll 8
    for (int k = 0; k < 512; k += 4) {
        ushort4 w4 = *(const ushort4*)(wr + k);
        ushort4 x4 = *(const ushort4*)(xr + k);
        acc += b2f(w4.x) * b2f(x4.x) + b2f(w4.y) * b2f(x4.y) +
               b2f(w4.z) * b2f(x4.z) + b2f(w4.w) * b2f(x4.w);
    }
    BC[(size_t)(m + r) * 32 + j] = tanhf(acc + bias[j]);
}

// ---------------------------------------------------------------------------
// Sequential SSM scan. 1 block per batch, 512 threads (thread t = channel d).
// Chunked LDS staging (8 steps / chunk, double-buffered): global loads issued
// at p==0, LDS-written at p==7 (issue-early/write-late) so barrier vmcnt drains
// see landed loads. yg buffered in registers, flushed once per chunk.
// One barrier per step; DPP wave reduce; partials double-buffered on step parity.
__global__ __launch_bounds__(512) void scan_kernel(
    const float* __restrict__ BC, const unsigned short* __restrict__ xconv,
    const unsigned short* __restrict__ gres, const float* __restrict__ Aw,
    const float* __restrict__ Dw, const float* __restrict__ sng,
    const float* __restrict__ snb, unsigned short* __restrict__ yg)
{
    __shared__ __align__(16) unsigned short lds_x[2][4096];
    __shared__ __align__(16) unsigned short lds_g[2][4096];
    __shared__ __align__(16) float lds_bc[2][256];
    __shared__ __align__(16) float lds_s1[2][8];
    __shared__ __align__(16) float lds_s2[2][8];
    int b = blockIdx.x, t = threadIdx.x;
    float st[16], tA[16], g[16], bb[16];
#pragma unroll
    for (int j = 0; j < 16; ++j) {
        st[j] = 0.0f;
        tA[j] = tanhf(Aw[t * 16 + j]);
        g[j]  = sng[t * 16 + j];
        bb[j] = snb[t * 16 + j];
    }
    float Dd = Dw[t];
    const size_t base = (size_t)b * 400;
    // stage chunk 0
    {
        size_t o = base * 512 + t * 8;
        *(ushort8*)(&lds_x[0][t * 8]) = *(const ushort8*)(xconv + o);
        *(ushort8*)(&lds_g[0][t * 8]) = *(const ushort8*)(gres + o);
        if (t < 64) *(float4*)(&lds_bc[0][t * 4]) = *(const float4*)(BC + base * 32 + t * 4);
    }
    __syncthreads();
    int cur = 0;
    ushort8 xs_r, gs_r; float4 bc_r;
    unsigned short yr[8];
    for (int l = 0; l < 400; ++l) {
        int p = l & 7;
        if (p == 0 && l + 8 < 400) {           // issue next-chunk loads (held in regs)
            size_t o = (base + l + 8) * 512 + t * 8;
            xs_r = *(const ushort8*)(xconv + o);
            gs_r = *(const ushort8*)(gres + o);
            if (t < 64) bc_r = *(const float4*)(BC + (base + l + 8) * 32 + t * 4);
        }
        float4 B4[4], C4[4];
#pragma unroll
        for (int q = 0; q < 4; ++q) {
            B4[q] = *(const float4*)(&lds_bc[cur][p * 32 + q * 4]);
            C4[q] = *(const float4*)(&lds_bc[cur][p * 32 + 16 + q * 4]);
        }
        float Btv[16], Ctv[16];
#pragma unroll
        for (int q = 0; q < 4; ++q) {
            Btv[q*4]=B4[q].x; Btv[q*4+1]=B4[q].y; Btv[q*4+2]=B4[q].z; Btv[q*4+3]=B4[q].w;
            Ctv[q*4]=C4[q].x; Ctv[q*4+1]=C4[q].y; Ctv[q*4+2]=C4[q].z; Ctv[q*4+3]=C4[q].w;
        }
        float xt = b2f(lds_x[cur][p * 512 + t]);
        float gr = b2f(lds_g[cur][p * 512 + t]);
        float oa = xt * Dd, ob = 0.0f;
#pragma unroll
        for (int j = 0; j < 16; j += 2) {
            st[j]     += Btv[j];     oa += st[j]     * Ctv[j];
            st[j + 1] += Btv[j + 1]; ob += st[j + 1] * Ctv[j + 1];
        }
        yr[p] = f2b((oa + ob) * gr);
        float a0 = 0.f, a1 = 0.f, q0 = 0.f, q1 = 0.f;
#pragma unroll
        for (int j = 0; j < 16; j += 2) {
            st[j]     *= tA[j];     a0 += st[j];     q0 += st[j]     * st[j];
            st[j + 1] *= tA[j + 1]; a1 += st[j + 1]; q1 += st[j + 1] * st[j + 1];
        }
        float s1 = wave_sum63(a0 + a1);
        float s2 = wave_sum63(q0 + q1);
        if (p == 7) {
            if (l + 1 < 400) {                 // write staged chunk into buffer cur^1
                *(ushort8*)(&lds_x[cur ^ 1][t * 8]) = xs_r;
                *(ushort8*)(&lds_g[cur ^ 1][t * 8]) = gs_r;
                if (t < 64) *(float4*)(&lds_bc[cur ^ 1][t * 4]) = bc_r;
            }
#pragma unroll
            for (int q = 0; q < 8; ++q)        // flush 8 steps of yg
                yg[(base + l - 7 + q) * 512 + t] = yr[q];
        }
        if ((t & 63) == 63) { lds_s1[l & 1][t >> 6] = s1; lds_s2[l & 1][t >> 6] = s2; }
        __syncthreads();                        // the ONLY barrier
        float4 p0v = *(const float4*)&lds_s1[l & 1][0];
        float4 p1v = *(const float4*)&lds_s1[l & 1][4];
        float4 r0v = *(const float4*)&lds_s2[l & 1][0];
        float4 r1v = *(const float4*)&lds_s2[l & 1][4];
        float S1 = ((p0v.x + p0v.y) + (p0v.z + p0v.w)) + ((p1v.x + p1v.y) + (p1v.z + p1v.w));
        float S2 = ((r0v.x + r0v.y) + (r0v.z + r0v.w)) + ((r1v.x + r1v.y) + (r1v.z + r1v.w));
        float mu = S1 * (1.0f / 8192.0f);
        float var = S2 * (1.0f / 8192.0f) - mu * mu;
        float rs = rsqrtf(var + 1e-5f);
#pragma unroll
        for (int j = 0; j < 16; ++j) {
            float rg = rs * g[j];
            float cc = fmaf(-mu, rg, bb[j]);
            st[j] = fmaf(st[j], rg, cc);
        }
        if (p == 7) cur ^= 1;
    }
}

// ---------------------------------------------------------------------------
// mean over L then FC (37 classes). 1 block per batch.
__global__ __launch_bounds__(256) void poolfc_kernel(
    const float* __restrict__ h, const float* __restrict__ fcw,
    const float* __restrict__ fcb, float* __restrict__ out)
{
    __shared__ float ps[256];
    int b = blockIdx.x, t = threadIdx.x;
    float s = 0.0f;
    for (int l = 0; l < 400; ++l) s += h[((size_t)b * 400 + l) * 256 + t];
    ps[t] = s * (1.0f / 400.0f);
    __syncthreads();
    if (t < 37) {
        float acc = fcb[t];
        for (int o = 0; o < 256; ++o) acc += ps[o] * fcw[t * 256 + o];
        out[b * 37 + t] = acc;
    }
}

// ---------------------------------------------------------------------------
extern "C" void kernel_launch(void* const* d_in, const int* in_sizes, int n_in,
                              void* d_out, int out_size, void* d_ws, size_t ws_size,
                              hipStream_t stream)
{
    const float* x         = (const float*)d_in[0];
    const float* conv1_w   = (const float*)d_in[1];
    const float* conv1_b   = (const float*)d_in[2];
    const float* conv2_w   = (const float*)d_in[3];
    const float* conv2_b   = (const float*)d_in[4];
    const float* ln_g      = (const float*)d_in[5];
    const float* ln_b      = (const float*)d_in[6];
    const float* inproj_w  = (const float*)d_in[7];
    const float* inproj_b  = (const float*)d_in[8];
    const float* dw_w      = (const float*)d_in[9];
    const float* dw_b      = (const float*)d_in[10];
    const float* xproj_w   = (const float*)d_in[11];
    const float* xproj_b   = (const float*)d_in[12];
    const float* A         = (const float*)d_in[13];
    const float* D         = (const float*)d_in[14];
    const float* sn_g      = (const float*)d_in[15];
    const float* sn_b      = (const float*)d_in[16];
    const float* outproj_w = (const float*)d_in[17];
    const float* outproj_b = (const float*)d_in[18];
    const float* fc_w      = (const float*)d_in[19];
    const float* fc_b      = (const float*)d_in[20];
    float* out = (float*)d_out;

    const int M = 51200; // B*L

    if (ws_size < 243007488u) return;
    char* ws = (char*)d_ws;
    float*          h    = (float*)(ws);
    unsigned short* hn   = (unsigned short*)(ws + 52428800);
    unsigned short* h1   = (unsigned short*)(ws + 52428800);
    unsigned short* xp_c = (unsigned short*)(ws + 78643200);
    unsigned short* yg   = (unsigned short*)(ws + 78643200);
    unsigned short* grs  = (unsigned short*)(ws + 131072000);
    unsigned short* xcv  = (unsigned short*)(ws + 183500800);
    float*          BC   = (float*)(ws + 235929600);
    unsigned short* wbuf = (unsigned short*)(ws + 242483200);

    conv1_kernel<<<128 * 8, 256, 0, stream>>>(x, conv1_w, conv1_b, h1);
    reorder_w2_kernel<<<768, 256, 0, stream>>>(conv2_w, wbuf);
    gemm_conv2<<<(M / 128) * 2, 256, 0, stream>>>(h1, wbuf, conv2_b, h);

    for (int i = 0; i < 2; ++i) {
        ln_kernel<<<M / 4, 256, 0, stream>>>(h, ln_g + i * 256, ln_b + i * 256, hn);
        castw_kernel<<<1024, 256, 0, stream>>>(inproj_w + (size_t)i * 262144, wbuf, 262144);
        gemm_bt<0><<<(M / 128) * 4, 256, 0, stream>>>(hn, wbuf, inproj_b + i * 1024, nullptr,
                                                      xp_c, 512, 256, 256, 512);
        gemm_bt<1><<<(M / 128) * 4, 256, 0, stream>>>(hn, wbuf + 131072, inproj_b + i * 1024 + 512,
                                                      nullptr, grs, 512, 256, 256, 512);
        dwconv_kernel<<<1024, 256, 0, stream>>>(xp_c, dw_w + i * 1536, dw_b + i * 512, xcv);
        castw_kernel<<<64, 256, 0, stream>>>(xproj_w + i * 16384, wbuf, 16384);
        xproj_kernel<<<M / 8, 256, 0, stream>>>(xcv, wbuf, xproj_b + i * 32, BC);
        scan_kernel<<<128, 512, 0, stream>>>(BC, xcv, grs, A + i * 8192, D + i * 512,
                                             sn_g + i * 8192, sn_b + i * 8192, yg);
        castw_kernel<<<512, 256, 0, stream>>>(outproj_w + (size_t)i * 131072, wbuf, 131072);
        gemm_bt<3><<<(M / 128) * 2, 256, 0, stream>>>(yg, wbuf, outproj_b + i * 256, h, h,
                                                      256, 512, 512, 256);
    }
    poolfc_kernel<<<128, 256, 0, stream>>>(h, fc_w, fc_b, out);
}

// Round 6
// 1181.871 us; speedup vs baseline: 1.2787x; 1.0594x over previous
//
#include <hip/hip_runtime.h>
#include <hip/hip_bf16.h>
#include <math.h>

#define DEVINL __device__ __forceinline__

typedef __attribute__((ext_vector_type(4))) float  f32x4;
typedef __attribute__((ext_vector_type(8))) __bf16 bf16x8;
typedef __attribute__((ext_vector_type(8))) unsigned short ushort8;

DEVINL float b2f(unsigned short u) {
    union { unsigned int i; float f; } v; v.i = ((unsigned int)u) << 16; return v.f;
}
DEVINL unsigned short f2b(float f) {
    union { float f; unsigned int i; } v; v.f = f;
    unsigned int u = v.i;
    unsigned int r = (u + 0x7fffu + ((u >> 16) & 1u)) >> 16;
    return (unsigned short)r;
}
DEVINL float gelu_exact(float x) {
    return 0.5f * x * (1.0f + erff(x * 0.70710678118654752440f));
}

// Barrier that drains ONLY LDS (lgkmcnt), leaving global loads/stores in
// flight across it (unlike __syncthreads, which drains vmcnt(0) too).
DEVINL void bar_lgkm() {
    asm volatile("s_waitcnt lgkmcnt(0)" ::: "memory");
    __builtin_amdgcn_s_barrier();
    __builtin_amdgcn_sched_barrier(0);
}

// LDS XOR swizzle (T2): permute 8-element groups within a 64-elem row by row&7.
// Applied to BOTH write and read sides of GEMM tile staging.
DEVINL int swz(int off) { return off ^ (((off >> 6) & 7) << 3); }

// DPP-based wave64 sum: result valid in lane 63 of each wave.
template <int CTRL>
DEVINL float dpp_add(float x) {
    int xi = __builtin_bit_cast(int, x);
    int yi = __builtin_amdgcn_update_dpp(0, xi, CTRL, 0xf, 0xf, true);
    return x + __builtin_bit_cast(float, yi);
}
DEVINL float wave_sum63(float x) {
    x = dpp_add<0x111>(x);   // row_shr:1
    x = dpp_add<0x112>(x);   // row_shr:2
    x = dpp_add<0x114>(x);   // row_shr:4
    x = dpp_add<0x118>(x);   // row_shr:8
    x = dpp_add<0x142>(x);   // row_bcast:15
    x = dpp_add<0x143>(x);   // row_bcast:31
    return x;                // lane 63 holds the full 64-lane sum
}

// ---------------------------------------------------------------------------
// conv1 (Cin=8 -> 256, k=3, pad=1) + ReLU, output bf16.
__global__ __launch_bounds__(256) void conv1_kernel(
    const float* __restrict__ x, const float* __restrict__ w,
    const float* __restrict__ bias, unsigned short* __restrict__ h1)
{
    __shared__ float xs[52 * 8];
    int b = blockIdx.x >> 3, tile = blockIdx.x & 7;
    int p0 = tile * 50;
    int t = threadIdx.x;
    for (int i = t; i < 416; i += 256) {
        int p = i >> 3, c = i & 7;
        int lp = p0 + p - 1;
        xs[i] = (lp >= 0 && lp < 400) ? x[((size_t)b * 400 + lp) * 8 + c] : 0.0f;
    }
    float wr[24];
    const float4* wp = (const float4*)(w + t * 24);
#pragma unroll
    for (int i = 0; i < 6; ++i) {
        float4 v4 = wp[i];
        wr[i * 4] = v4.x; wr[i * 4 + 1] = v4.y; wr[i * 4 + 2] = v4.z; wr[i * 4 + 3] = v4.w;
    }
    float bs = bias[t];
    __syncthreads();
#pragma unroll 2
    for (int p = 0; p < 50; ++p) {
        float acc = bs;
#pragma unroll
        for (int dt = 0; dt < 3; ++dt)
#pragma unroll
            for (int c = 0; c < 8; ++c)
                acc += xs[(p + dt) * 8 + c] * wr[c * 3 + dt];
        h1[((size_t)b * 400 + p0 + p) * 256 + t] = f2b(fmaxf(acc, 0.0f));
    }
}

// conv2 weight reorder (o, ci, t) -> w2r[o, t*256+ci] bf16
__global__ void reorder_w2_kernel(const float* __restrict__ w, unsigned short* __restrict__ out)
{
    int idx = blockIdx.x * 256 + threadIdx.x;
    if (idx >= 256 * 768) return;
    int o = idx / 768, r = idx % 768;
    int tpos = r / 256, ci = r % 256;
    out[idx] = f2b(w[o * 768 + ci * 3 + tpos]);
}

__global__ void castw_kernel(const float* __restrict__ in, unsigned short* __restrict__ out, int n)
{
    int i = blockIdx.x * 256 + threadIdx.x;
    if (i < n) out[i] = f2b(in[i]);
}

// ---------------------------------------------------------------------------
// LayerNorm over dm=256 per row, fp32 in -> bf16 out. 4 rows/block (1/wave).
__global__ __launch_bounds__(256) void ln_kernel(
    const float* __restrict__ h, const float* __restrict__ g,
    const float* __restrict__ bta, unsigned short* __restrict__ out)
{
    int w = threadIdx.x >> 6, l = threadIdx.x & 63;
    int row = blockIdx.x * 4 + w;
    const float* p = h + (size_t)row * 256 + l * 4;
    float4 v = *(const float4*)p;
    float s  = v.x + v.y + v.z + v.w;
    float s2 = v.x * v.x + v.y * v.y + v.z * v.z + v.w * v.w;
#pragma unroll
    for (int m = 1; m < 64; m <<= 1) { s += __shfl_xor(s, m); s2 += __shfl_xor(s2, m); }
    float mu = s * (1.0f / 256.0f);
    float var = s2 * (1.0f / 256.0f) - mu * mu;
    float rs = rsqrtf(var + 1e-5f);
    float4 gg = *(const float4*)(g + l * 4);
    float4 bb = *(const float4*)(bta + l * 4);
    ushort4 o;
    o.x = f2b((v.x - mu) * rs * gg.x + bb.x);
    o.y = f2b((v.y - mu) * rs * gg.y + bb.y);
    o.z = f2b((v.z - mu) * rs * gg.z + bb.z);
    o.w = f2b((v.w - mu) * rs * gg.w + bb.w);
    *(ushort4*)(out + (size_t)row * 256 + l * 4) = o;
}

// ---------------------------------------------------------------------------
// bf16 GEMM: C(MxN) = A(MxK, lda) * Bt(NxK)^T, epilogue variants.
// LDS tiles XOR-swizzled (write+read) to kill the 16-way bank conflict.
template <int EPI>
__global__ __launch_bounds__(256) void gemm_bt(
    const unsigned short* __restrict__ A, const unsigned short* __restrict__ Bt,
    const float* __restrict__ bias, const float* __restrict__ res,
    void* __restrict__ Cout, int N, int K, int lda, int ldc)
{
    __shared__ unsigned short As[128 * 64];
    __shared__ unsigned short Bs[128 * 64];
    const int nbn = N >> 7;
    int bm = blockIdx.x / nbn, bn = blockIdx.x % nbn;
    int t = threadIdx.x, l = t & 63, w = t >> 6;
    int wm = w & 1, wn = w >> 1;
    f32x4 acc[4][4] = {};
    const int ktn = K >> 6;
    for (int kt = 0; kt < ktn; ++kt) {
#pragma unroll
        for (int i = 0; i < 4; ++i) {
            int off = (i * 256 + t) * 8;
            int row = off >> 6, col = off & 63;
            ushort8 va = *(const ushort8*)(A + (size_t)(bm * 128 + row) * lda + kt * 64 + col);
            *(ushort8*)(As + swz(off)) = va;
            ushort8 vb = *(const ushort8*)(Bt + (size_t)(bn * 128 + row) * K + kt * 64 + col);
            *(ushort8*)(Bs + swz(off)) = vb;
        }
        __syncthreads();
#pragma unroll
        for (int kk = 0; kk < 2; ++kk) {
            bf16x8 af[4], bfr[4];
#pragma unroll
            for (int i = 0; i < 4; ++i) {
                af[i]  = *(const bf16x8*)(As + swz((wm * 64 + i * 16 + (l & 15)) * 64 + kk * 32 + (l >> 4) * 8));
                bfr[i] = *(const bf16x8*)(Bs + swz((wn * 64 + i * 16 + (l & 15)) * 64 + kk * 32 + (l >> 4) * 8));
            }
#pragma unroll
            for (int i = 0; i < 4; ++i)
#pragma unroll
                for (int j = 0; j < 4; ++j)
                    acc[i][j] = __builtin_amdgcn_mfma_f32_16x16x32_bf16(af[i], bfr[j], acc[i][j], 0, 0, 0);
        }
        __syncthreads();
    }
    int r0 = bm * 128 + wm * 64 + (l >> 4) * 4;
    int c0 = bn * 128 + wn * 64 + (l & 15);
#pragma unroll
    for (int i = 0; i < 4; ++i) {
#pragma unroll
        for (int j = 0; j < 4; ++j) {
            int col = c0 + j * 16;
            float bb = bias[col];
#pragma unroll
            for (int q = 0; q < 4; ++q) {
                int row = r0 + i * 16 + q;
                size_t idx = (size_t)row * ldc + col;
                float v = acc[i][j][q] + bb;
                if (EPI == 0)       ((unsigned short*)Cout)[idx] = f2b(v);
                else if (EPI == 1)  ((unsigned short*)Cout)[idx] = f2b(gelu_exact(v));
                else                ((float*)Cout)[idx] = v + res[idx];
            }
        }
    }
}

// ---------------------------------------------------------------------------
// conv2 as GEMM with FUSED im2col staging. ReLU epilogue, fp32 out. Swizzled LDS.
__global__ __launch_bounds__(256) void gemm_conv2(
    const unsigned short* __restrict__ h1, const unsigned short* __restrict__ Bt,
    const float* __restrict__ bias, float* __restrict__ Cout)
{
    __shared__ unsigned short As[128 * 64];
    __shared__ unsigned short Bs[128 * 64];
    int bm = blockIdx.x >> 1, bn = blockIdx.x & 1;
    int t = threadIdx.x, l = t & 63, w = t >> 6;
    int wm = w & 1, wn = w >> 1;
    f32x4 acc[4][4] = {};
    for (int kt = 0; kt < 12; ++kt) {
        int tpos = kt >> 2;
        int cbase = (kt & 3) * 64;
#pragma unroll
        for (int i = 0; i < 4; ++i) {
            int off = (i * 256 + t) * 8;
            int row = off >> 6, col = off & 63;
            int m = bm * 128 + row;
            int b = m / 400, ll = m % 400;
            int lp = ll + tpos - 1;
            ushort8 va = (ushort8)0;
            if (lp >= 0 && lp < 400)
                va = *(const ushort8*)(h1 + ((size_t)(b * 400 + lp) * 256 + cbase + col));
            *(ushort8*)(As + swz(off)) = va;
            ushort8 vb = *(const ushort8*)(Bt + (size_t)(bn * 128 + row) * 768 + kt * 64 + col);
            *(ushort8*)(Bs + swz(off)) = vb;
        }
        __syncthreads();
#pragma unroll
        for (int kk = 0; kk < 2; ++kk) {
            bf16x8 af[4], bfr[4];
#pragma unroll
            for (int i = 0; i < 4; ++i) {
                af[i]  = *(const bf16x8*)(As + swz((wm * 64 + i * 16 + (l & 15)) * 64 + kk * 32 + (l >> 4) * 8));
                bfr[i] = *(const bf16x8*)(Bs + swz((wn * 64 + i * 16 + (l & 15)) * 64 + kk * 32 + (l >> 4) * 8));
            }
#pragma unroll
            for (int i = 0; i < 4; ++i)
#pragma unroll
                for (int j = 0; j < 4; ++j)
                    acc[i][j] = __builtin_amdgcn_mfma_f32_16x16x32_bf16(af[i], bfr[j], acc[i][j], 0, 0, 0);
        }
        __syncthreads();
    }
    int r0 = bm * 128 + wm * 64 + (l >> 4) * 4;
    int c0 = bn * 128 + wn * 64 + (l & 15);
#pragma unroll
    for (int i = 0; i < 4; ++i)
#pragma unroll
        for (int j = 0; j < 4; ++j) {
            int col = c0 + j * 16;
            float bb = bias[col];
#pragma unroll
            for (int q = 0; q < 4; ++q) {
                int row = r0 + i * 16 + q;
                Cout[(size_t)row * 256 + col] = fmaxf(acc[i][j][q] + bb, 0.0f);
            }
        }
}

// ---------------------------------------------------------------------------
// depthwise conv (k=3, pad=1) + GELU; bf16 in/out; register-sliding window.
__global__ __launch_bounds__(256) void dwconv_kernel(
    const unsigned short* __restrict__ xp, const float* __restrict__ w,
    const float* __restrict__ bias, unsigned short* __restrict__ out)
{
    int b = blockIdx.x >> 3, tile = blockIdx.x & 7;
    int p0 = tile * 50;
    int t = threadIdx.x;
    int c = t * 2;
    float w00 = w[c * 3], w01 = w[c * 3 + 1], w02 = w[c * 3 + 2];
    float w10 = w[c * 3 + 3], w11 = w[c * 3 + 4], w12 = w[c * 3 + 5];
    float b0 = bias[c], b1 = bias[c + 1];
    const size_t rowb = (size_t)b * 400;
    int l = p0;
    unsigned int r0 = (l - 1 >= 0) ? *(const unsigned int*)(xp + (rowb + l - 1) * 512 + c) : 0u;
    unsigned int r1 = *(const unsigned int*)(xp + (rowb + l) * 512 + c);
    for (int q = 0; q < 50; ++q, ++l) {
        unsigned int r2 = (l + 1 < 400) ? *(const unsigned int*)(xp + (rowb + l + 1) * 512 + c) : 0u;
        float a0 = b0 + b2f((unsigned short)(r0 & 0xffff)) * w00
                      + b2f((unsigned short)(r1 & 0xffff)) * w01
                      + b2f((unsigned short)(r2 & 0xffff)) * w02;
        float a1 = b1 + b2f((unsigned short)(r0 >> 16)) * w10
                      + b2f((unsigned short)(r1 >> 16)) * w11
                      + b2f((unsigned short)(r2 >> 16)) * w12;
        unsigned int o = (unsigned int)f2b(gelu_exact(a0)) | ((unsigned int)f2b(gelu_exact(a1)) << 16);
        *(unsigned int*)(out + (rowb + l) * 512 + c) = o;
        r0 = r1; r1 = r2;
    }
}

// ---------------------------------------------------------------------------
// xproj: BC(m,32) = tanh(x_conv(m,512) @ W^T(32x512) + b). 8 rows/block.
__global__ __launch_bounds__(256) void xproj_kernel(
    const unsigned short* __restrict__ xc, const unsigned short* __restrict__ w,
    const float* __restrict__ bias, float* __restrict__ BC)
{
    __shared__ unsigned short wsh[32 * 516];
    __shared__ unsigned short xs[8 * 512];
    int t = threadIdx.x;
    int m = blockIdx.x * 8;
    for (int i = t; i < 4096; i += 256) {
        int e = i * 4; int j = e / 512, k = e % 512;
        *(ushort4*)(wsh + j * 516 + k) = *(const ushort4*)(w + j * 512 + k);
    }
    for (int i = t; i < 1024; i += 256) {
        int e = i * 4;
        *(ushort4*)(xs + e) = *(const ushort4*)(xc + (size_t)m * 512 + e);
    }
    __syncthreads();
    int r = t >> 5, j = t & 31;
    const unsigned short* wr = wsh + j * 516;
    const unsigned short* xr = xs + r * 512;
    float acc = 0.0f;
#pragma unroll 8
    for (int k = 0; k < 512; k += 4) {
        ushort4 w4 = *(const ushort4*)(wr + k);
        ushort4 x4 = *(const ushort4*)(xr + k);
        acc += b2f(w4.x) * b2f(x4.x) + b2f(w4.y) * b2f(x4.y) +
               b2f(w4.z) * b2f(x4.z) + b2f(w4.w) * b2f(x4.w);
    }
    BC[(size_t)(m + r) * 32 + j] = tanhf(acc + bias[j]);
}

// ---------------------------------------------------------------------------
// Sequential SSM scan. 1 block per batch, 512 threads (thread t = channel d).
// Chunked LDS staging (8 steps/chunk, double-buffered): loads issued at p==0,
// LDS-written at p==7. Barriers drain ONLY lgkmcnt (bar_lgkm) so the prefetch
// loads and yg stores stay in flight across all intermediate barriers.
__global__ __launch_bounds__(512) void scan_kernel(
    const float* __restrict__ BC, const unsigned short* __restrict__ xconv,
    const unsigned short* __restrict__ gres, const float* __restrict__ Aw,
    const float* __restrict__ Dw, const float* __restrict__ sng,
    const float* __restrict__ snb, unsigned short* __restrict__ yg)
{
    __shared__ __align__(16) unsigned short lds_x[2][4096];
    __shared__ __align__(16) unsigned short lds_g[2][4096];
    __shared__ __align__(16) float lds_bc[2][256];
    __shared__ __align__(16) float lds_s1[2][8];
    __shared__ __align__(16) float lds_s2[2][8];
    int b = blockIdx.x, t = threadIdx.x;
    float st[16], tA[16], g[16], bb[16];
#pragma unroll
    for (int j = 0; j < 16; ++j) {
        st[j] = 0.0f;
        tA[j] = tanhf(Aw[t * 16 + j]);
        g[j]  = sng[t * 16 + j];
        bb[j] = snb[t * 16 + j];
    }
    float Dd = Dw[t];
    const size_t base = (size_t)b * 400;
    // stage chunk 0
    {
        size_t o = base * 512 + t * 8;
        *(ushort8*)(&lds_x[0][t * 8]) = *(const ushort8*)(xconv + o);
        *(ushort8*)(&lds_g[0][t * 8]) = *(const ushort8*)(gres + o);
        if (t < 64) *(float4*)(&lds_bc[0][t * 4]) = *(const float4*)(BC + base * 32 + t * 4);
    }
    bar_lgkm();
    int cur = 0;
    ushort8 xs_r, gs_r; float4 bc_r;
    for (int l = 0; l < 400; ++l) {
        int p = l & 7;
        if (p == 0 && l + 8 < 400) {           // issue next-chunk loads (stay in flight 7 steps)
            size_t o = (base + l + 8) * 512 + t * 8;
            xs_r = *(const ushort8*)(xconv + o);
            gs_r = *(const ushort8*)(gres + o);
            if (t < 64) bc_r = *(const float4*)(BC + (base + l + 8) * 32 + t * 4);
        }
        float4 B4[4], C4[4];
#pragma unroll
        for (int q = 0; q < 4; ++q) {
            B4[q] = *(const float4*)(&lds_bc[cur][p * 32 + q * 4]);
            C4[q] = *(const float4*)(&lds_bc[cur][p * 32 + 16 + q * 4]);
        }
        float Btv[16], Ctv[16];
#pragma unroll
        for (int q = 0; q < 4; ++q) {
            Btv[q*4]=B4[q].x; Btv[q*4+1]=B4[q].y; Btv[q*4+2]=B4[q].z; Btv[q*4+3]=B4[q].w;
            Ctv[q*4]=C4[q].x; Ctv[q*4+1]=C4[q].y; Ctv[q*4+2]=C4[q].z; Ctv[q*4+3]=C4[q].w;
        }
        float xt = b2f(lds_x[cur][p * 512 + t]);
        float gr = b2f(lds_g[cur][p * 512 + t]);
        float oa = xt * Dd, ob = 0.0f;
#pragma unroll
        for (int j = 0; j < 16; j += 2) {
            st[j]     += Btv[j];     oa += st[j]     * Ctv[j];
            st[j + 1] += Btv[j + 1]; ob += st[j + 1] * Ctv[j + 1];
        }
        yg[(base + l) * 512 + t] = f2b((oa + ob) * gr);   // fire-and-forget (no drain)
        float a0 = 0.f, a1 = 0.f, q0 = 0.f, q1 = 0.f;
#pragma unroll
        for (int j = 0; j < 16; j += 2) {
            st[j]     *= tA[j];     a0 += st[j];     q0 += st[j]     * st[j];
            st[j + 1] *= tA[j + 1]; a1 += st[j + 1]; q1 += st[j + 1] * st[j + 1];
        }
        float s1 = wave_sum63(a0 + a1);
        float s2 = wave_sum63(q0 + q1);
        if (p == 7 && l + 1 < 400) {           // write staged chunk into buffer cur^1
            *(ushort8*)(&lds_x[cur ^ 1][t * 8]) = xs_r;    // compiler inserts vmcnt wait here
            *(ushort8*)(&lds_g[cur ^ 1][t * 8]) = gs_r;
            if (t < 64) *(float4*)(&lds_bc[cur ^ 1][t * 4]) = bc_r;
        }
        if ((t & 63) == 63) { lds_s1[l & 1][t >> 6] = s1; lds_s2[l & 1][t >> 6] = s2; }
        bar_lgkm();                             // the ONLY barrier (lgkm-only drain)
        float4 p0v = *(const float4*)&lds_s1[l & 1][0];
        float4 p1v = *(const float4*)&lds_s1[l & 1][4];
        float4 r0v = *(const float4*)&lds_s2[l & 1][0];
        float4 r1v = *(const float4*)&lds_s2[l & 1][4];
        float S1 = ((p0v.x + p0v.y) + (p0v.z + p0v.w)) + ((p1v.x + p1v.y) + (p1v.z + p1v.w));
        float S2 = ((r0v.x + r0v.y) + (r0v.z + r0v.w)) + ((r1v.x + r1v.y) + (r1v.z + r1v.w));
        float mu = S1 * (1.0f / 8192.0f);
        float var = S2 * (1.0f / 8192.0f) - mu * mu;
        float rs = rsqrtf(var + 1e-5f);
#pragma unroll
        for (int j = 0; j < 16; ++j) {
            float rg = rs * g[j];
            float cc = fmaf(-mu, rg, bb[j]);
            st[j] = fmaf(st[j], rg, cc);
        }
        if (p == 7) cur ^= 1;
    }
}

// ---------------------------------------------------------------------------
// mean over L then FC (37 classes). 1 block per batch.
__global__ __launch_bounds__(256) void poolfc_kernel(
    const float* __restrict__ h, const float* __restrict__ fcw,
    const float* __restrict__ fcb, float* __restrict__ out)
{
    __shared__ float ps[256];
    int b = blockIdx.x, t = threadIdx.x;
    float s = 0.0f;
    for (int l = 0; l < 400; ++l) s += h[((size_t)b * 400 + l) * 256 + t];
    ps[t] = s * (1.0f / 400.0f);
    __syncthreads();
    if (t < 37) {
        float acc = fcb[t];
        for (int o = 0; o < 256; ++o) acc += ps[o] * fcw[t * 256 + o];
        out[b * 37 + t] = acc;
    }
}

// ---------------------------------------------------------------------------
extern "C" void kernel_launch(void* const* d_in, const int* in_sizes, int n_in,
                              void* d_out, int out_size, void* d_ws, size_t ws_size,
                              hipStream_t stream)
{
    const float* x         = (const float*)d_in[0];
    const float* conv1_w   = (const float*)d_in[1];
    const float* conv1_b   = (const float*)d_in[2];
    const float* conv2_w   = (const float*)d_in[3];
    const float* conv2_b   = (const float*)d_in[4];
    const float* ln_g      = (const float*)d_in[5];
    const float* ln_b      = (const float*)d_in[6];
    const float* inproj_w  = (const float*)d_in[7];
    const float* inproj_b  = (const float*)d_in[8];
    const float* dw_w      = (const float*)d_in[9];
    const float* dw_b      = (const float*)d_in[10];
    const float* xproj_w   = (const float*)d_in[11];
    const float* xproj_b   = (const float*)d_in[12];
    const float* A         = (const float*)d_in[13];
    const float* D         = (const float*)d_in[14];
    const float* sn_g      = (const float*)d_in[15];
    const float* sn_b      = (const float*)d_in[16];
    const float* outproj_w = (const float*)d_in[17];
    const float* outproj_b = (const float*)d_in[18];
    const float* fc_w      = (const float*)d_in[19];
    const float* fc_b      = (const float*)d_in[20];
    float* out = (float*)d_out;

    const int M = 51200; // B*L

    if (ws_size < 243007488u) return;
    char* ws = (char*)d_ws;
    float*          h    = (float*)(ws);
    unsigned short* hn   = (unsigned short*)(ws + 52428800);
    unsigned short* h1   = (unsigned short*)(ws + 52428800);
    unsigned short* xp_c = (unsigned short*)(ws + 78643200);
    unsigned short* yg   = (unsigned short*)(ws + 78643200);
    unsigned short* grs  = (unsigned short*)(ws + 131072000);
    unsigned short* xcv  = (unsigned short*)(ws + 183500800);
    float*          BC   = (float*)(ws + 235929600);
    unsigned short* wbuf = (unsigned short*)(ws + 242483200);

    conv1_kernel<<<128 * 8, 256, 0, stream>>>(x, conv1_w, conv1_b, h1);
    reorder_w2_kernel<<<768, 256, 0, stream>>>(conv2_w, wbuf);
    gemm_conv2<<<(M / 128) * 2, 256, 0, stream>>>(h1, wbuf, conv2_b, h);

    for (int i = 0; i < 2; ++i) {
        ln_kernel<<<M / 4, 256, 0, stream>>>(h, ln_g + i * 256, ln_b + i * 256, hn);
        castw_kernel<<<1024, 256, 0, stream>>>(inproj_w + (size_t)i * 262144, wbuf, 262144);
        gemm_bt<0><<<(M / 128) * 4, 256, 0, stream>>>(hn, wbuf, inproj_b + i * 1024, nullptr,
                                                      xp_c, 512, 256, 256, 512);
        gemm_bt<1><<<(M / 128) * 4, 256, 0, stream>>>(hn, wbuf + 131072, inproj_b + i * 1024 + 512,
                                                      nullptr, grs, 512, 256, 256, 512);
        dwconv_kernel<<<1024, 256, 0, stream>>>(xp_c, dw_w + i * 1536, dw_b + i * 512, xcv);
        castw_kernel<<<64, 256, 0, stream>>>(xproj_w + i * 16384, wbuf, 16384);
        xproj_kernel<<<M / 8, 256, 0, stream>>>(xcv, wbuf, xproj_b + i * 32, BC);
        scan_kernel<<<128, 512, 0, stream>>>(BC, xcv, grs, A + i * 8192, D + i * 512,
                                             sn_g + i * 8192, sn_b + i * 8192, yg);
        castw_kernel<<<512, 256, 0, stream>>>(outproj_w + (size_t)i * 131072, wbuf, 131072);
        gemm_bt<3><<<(M / 128) * 2, 256, 0, stream>>>(yg, wbuf, outproj_b + i * 256, h, h,
                                                      256, 512, 512, 256);
    }
    poolfc_kernel<<<128, 256, 0, stream>>>(h, fc_w, fc_b, out);
}